// Round 6
// baseline (311.701 us; speedup 1.0000x reference)
//
#include <hip/hip_runtime.h>

#define NN    50000      // nodes
#define NE    800000     // edges (without self loops)
#define NET   850000     // NE + NN (with self loops)
#define NBUCK ((NN + 255) / 256)   // 196 dst-buckets of 256 nodes
#define MAXB  8192       // LDS capacity per bucket (avg 4352, sigma 66)

typedef __fp16 half2_t __attribute__((ext_vector_type(2)));

__device__ __forceinline__ float lrelu(float v) { return fmaxf(v, 0.2f * v); }
__device__ __forceinline__ float4 f4zero() { return make_float4(0.f, 0.f, 0.f, 0.f); }
__device__ __forceinline__ unsigned pk16(float a, float b) {
    half2_t h = __builtin_amdgcn_cvt_pkrtz(a, b);
    return __builtin_bit_cast(unsigned, h);
}
__device__ __forceinline__ float2 unpk16(unsigned u) {
    half2_t h = __builtin_bit_cast(half2_t, u);
    return make_float2((float)h.x, (float)h.y);
}

// ---------------------------------------------------------------------------
// GEMM1 + alpha1 fused (unchanged, verified R4)
// ---------------------------------------------------------------------------
__global__ __launch_bounds__(256) void gemm1_alpha_kernel(
    const float* __restrict__ x, const float* __restrict__ W,
    const float* __restrict__ att_s, const float* __restrict__ att_d,
    unsigned* __restrict__ hh, float* __restrict__ as, float* __restrict__ ad)
{
    __shared__ float Ws[64 * 128];
    __shared__ float xs[64 * 64];
    const int t  = threadIdx.x;
    const int n0 = blockIdx.x * 64;
    const int jc = t & 31;
    const int ng = t >> 5;

    float4 acc[8];
#pragma unroll
    for (int r = 0; r < 8; r++) acc[r] = f4zero();

    float4*       Ws4 = (float4*)Ws;
    float4*       xs4 = (float4*)xs;
    const float4* x4  = (const float4*)x;

    for (int kc = 0; kc < 128; kc += 64) {
        const float4* W4 = (const float4*)(W + kc * 128);
        for (int i = t; i < 64 * 32; i += 256) Ws4[i] = W4[i];
        for (int i = t; i < 64 * 16; i += 256) {
            int node = n0 + (i >> 4);
            xs4[i] = (node < NN) ? x4[node * 32 + (kc >> 2) + (i & 15)] : f4zero();
        }
        __syncthreads();

        for (int kk = 0; kk < 64; kk += 4) {
            float4 w0 = Ws4[(kk + 0) * 32 + jc];
            float4 w1 = Ws4[(kk + 1) * 32 + jc];
            float4 w2 = Ws4[(kk + 2) * 32 + jc];
            float4 w3 = Ws4[(kk + 3) * 32 + jc];
#pragma unroll
            for (int r = 0; r < 8; r++) {
                float4 xv = xs4[((ng * 8 + r) * 64 + kk) >> 2];
                acc[r].x += xv.x * w0.x + xv.y * w1.x + xv.z * w2.x + xv.w * w3.x;
                acc[r].y += xv.x * w0.y + xv.y * w1.y + xv.z * w2.y + xv.w * w3.y;
                acc[r].z += xv.x * w0.z + xv.y * w1.z + xv.z * w2.z + xv.w * w3.z;
                acc[r].w += xv.x * w0.w + xv.y * w1.w + xv.z * w2.w + xv.w * w3.w;
            }
        }
        __syncthreads();
    }

    const float4 sa4 = ((const float4*)att_s)[jc];
    const float4 da4 = ((const float4*)att_d)[jc];
#pragma unroll
    for (int r = 0; r < 8; r++) {
        const int node = n0 + ng * 8 + r;
        const bool ok  = node < NN;
        if (ok) {
            uint2 hp;
            hp.x = pk16(acc[r].x, acc[r].y);
            hp.y = pk16(acc[r].z, acc[r].w);
            ((uint2*)hh)[node * 32 + jc] = hp;
        }
        float ps = acc[r].x * sa4.x + acc[r].y * sa4.y + acc[r].z * sa4.z + acc[r].w * sa4.w;
        float pd = acc[r].x * da4.x + acc[r].y * da4.y + acc[r].z * da4.z + acc[r].w * da4.w;
        ps += __shfl_down(ps, 4);  pd += __shfl_down(pd, 4);
        ps += __shfl_down(ps, 2);  pd += __shfl_down(pd, 2);
        ps += __shfl_down(ps, 1);  pd += __shfl_down(pd, 1);
        if (ok && (jc & 7) == 0) {
            as[node * 4 + (jc >> 3)] = ps;
            ad[node * 4 + (jc >> 3)] = pd;
        }
    }
}

// ---------------------------------------------------------------------------
// GEMM2 + alpha2 fused (unchanged, verified R4)
// ---------------------------------------------------------------------------
__global__ __launch_bounds__(256) void gemm2_alpha_kernel(
    const float* __restrict__ x, const float* __restrict__ W,
    const float* __restrict__ att_s, const float* __restrict__ att_d,
    float* __restrict__ h, float* __restrict__ as, float* __restrict__ ad)
{
    __shared__ float Ws[128 * 64];
    __shared__ float xs[64 * 64];
    const int t  = threadIdx.x;
    const int n0 = blockIdx.x * 64;
    const int jc = t & 15;
    const int ng = t >> 4;

    float4 acc[4];
#pragma unroll
    for (int r = 0; r < 4; r++) acc[r] = f4zero();

    float4*       Ws4 = (float4*)Ws;
    float4*       xs4 = (float4*)xs;
    const float4* x4  = (const float4*)x;

    for (int i = t; i < 128 * 16; i += 256) Ws4[i] = ((const float4*)W)[i];

    for (int kc = 0; kc < 128; kc += 64) {
        __syncthreads();
        for (int i = t; i < 64 * 16; i += 256) {
            int node = n0 + (i >> 4);
            xs4[i] = (node < NN) ? x4[node * 32 + (kc >> 2) + (i & 15)] : f4zero();
        }
        __syncthreads();

        for (int kk = 0; kk < 64; kk += 4) {
            float4 w0 = Ws4[(kc + kk + 0) * 16 + jc];
            float4 w1 = Ws4[(kc + kk + 1) * 16 + jc];
            float4 w2 = Ws4[(kc + kk + 2) * 16 + jc];
            float4 w3 = Ws4[(kc + kk + 3) * 16 + jc];
#pragma unroll
            for (int r = 0; r < 4; r++) {
                float4 xv = xs4[((ng * 4 + r) * 64 + kk) >> 2];
                acc[r].x += xv.x * w0.x + xv.y * w1.x + xv.z * w2.x + xv.w * w3.x;
                acc[r].y += xv.x * w0.y + xv.y * w1.y + xv.z * w2.y + xv.w * w3.y;
                acc[r].z += xv.x * w0.z + xv.y * w1.z + xv.z * w2.z + xv.w * w3.z;
                acc[r].w += xv.x * w0.w + xv.y * w1.w + xv.z * w2.w + xv.w * w3.w;
            }
        }
    }

    const float4 sa4 = ((const float4*)att_s)[jc];
    const float4 da4 = ((const float4*)att_d)[jc];
#pragma unroll
    for (int r = 0; r < 4; r++) {
        const int node = n0 + ng * 4 + r;
        const bool ok  = node < NN;
        if (ok) ((float4*)h)[node * 16 + jc] = acc[r];
        float ps = acc[r].x * sa4.x + acc[r].y * sa4.y + acc[r].z * sa4.z + acc[r].w * sa4.w;
        float pd = acc[r].x * da4.x + acc[r].y * da4.y + acc[r].z * da4.z + acc[r].w * da4.w;
        ps += __shfl_down(ps, 8);  pd += __shfl_down(pd, 8);
        ps += __shfl_down(ps, 4);  pd += __shfl_down(pd, 4);
        ps += __shfl_down(ps, 2);  pd += __shfl_down(pd, 2);
        ps += __shfl_down(ps, 1);  pd += __shfl_down(pd, 1);
        if (ok && jc == 0) { as[node] = ps; ad[node] = pd; }
    }
}

// ---------------------------------------------------------------------------
// CSR build v2 (verified R5) + cold (dst per slot) emitted by bsort.
// ---------------------------------------------------------------------------
__global__ __launch_bounds__(1024) void bcount_kernel(const int* __restrict__ ei,
                                                      int* __restrict__ bcnt)
{
    __shared__ int lh[NBUCK];
    const int t = threadIdx.x;
    if (t < NBUCK) lh[t] = 0;
    __syncthreads();
    const int e = blockIdx.x * 1024 + t;
    if (e < NET) {
        const int d = (e < NE) ? ei[NE + e] : e - NE;
        atomicAdd(&lh[d >> 8], 1);
    }
    __syncthreads();
    if (t < NBUCK && lh[t]) atomicAdd(&bcnt[t], lh[t]);
}

__global__ __launch_bounds__(256) void bscan_kernel(const int* __restrict__ bcnt,
                                                    int* __restrict__ boff,
                                                    int* __restrict__ bcursor,
                                                    int* __restrict__ row_ptr)
{
    __shared__ int sh[256];
    const int t = threadIdx.x;
    const int v = (t < NBUCK) ? bcnt[t] : 0;
    sh[t] = v;
    __syncthreads();
#pragma unroll
    for (int off = 1; off < 256; off <<= 1) {
        int u = (t >= off) ? sh[t - off] : 0;
        __syncthreads();
        sh[t] += u;
        __syncthreads();
    }
    if (t < NBUCK) {
        const int ex = sh[t] - v;
        boff[t]    = ex;
        bcursor[t] = ex;
    }
    if (t == 0) { boff[NBUCK] = NET; row_ptr[NN] = NET; }
}

__global__ __launch_bounds__(1024) void bin_kernel(const int* __restrict__ ei,
                                                   int* __restrict__ bcursor,
                                                   uint2* __restrict__ pairs)
{
    __shared__ int hist[NBUCK], base[NBUCK], cur[NBUCK];
    const int t = threadIdx.x;
    if (t < NBUCK) { hist[t] = 0; cur[t] = 0; }
    __syncthreads();
    const int e = blockIdx.x * 1024 + t;
    int s = 0, d = 0, bk = 0;
    const bool ok = e < NET;
    if (ok) {
        if (e < NE) { s = ei[e]; d = ei[NE + e]; } else { s = d = e - NE; }
        bk = d >> 8;
        atomicAdd(&hist[bk], 1);
    }
    __syncthreads();
    if (t < NBUCK && hist[t]) base[t] = atomicAdd(&bcursor[t], hist[t]);
    __syncthreads();
    if (ok) {
        const int r = atomicAdd(&cur[bk], 1);
        pairs[base[bk] + r] = make_uint2((unsigned)s, (unsigned)d);
    }
}

__global__ __launch_bounds__(512) void bsort_kernel(const int* __restrict__ boff,
                                                    const uint2* __restrict__ pairs,
                                                    int* __restrict__ row_ptr,
                                                    int* __restrict__ col,
                                                    int* __restrict__ cold)
{
    __shared__ int hist[256], cur[256], sh[256];
    __shared__ int outl[MAXB];
    __shared__ int outd[MAXB];
    const int b = blockIdx.x, t = threadIdx.x;
    const int gbeg = boff[b], gend = boff[b + 1];
    const int m = gend - gbeg;
    if (t < 256) hist[t] = 0;
    __syncthreads();
    for (int i = t; i < m; i += 512)
        atomicAdd(&hist[pairs[gbeg + i].y & 255], 1);
    __syncthreads();
    if (t < 256) sh[t] = hist[t];
    __syncthreads();
#pragma unroll
    for (int off = 1; off < 256; off <<= 1) {
        int u = (t < 256 && t >= off) ? sh[t - off] : 0;
        __syncthreads();
        if (t < 256) sh[t] += u;
        __syncthreads();
    }
    if (t < 256) {
        const int ex = sh[t] - hist[t];
        cur[t] = ex;
        const int node = (b << 8) + t;
        if (node < NN) row_ptr[node] = gbeg + ex;
    }
    __syncthreads();
    for (int i = t; i < m; i += 512) {
        const uint2 p = pairs[gbeg + i];
        const int r = atomicAdd(&cur[p.y & 255], 1);
        outl[r] = (int)p.x;
        outd[r] = (int)p.y;
    }
    __syncthreads();
    for (int i = t; i < m; i += 512) {
        col[gbeg + i]  = outl[i];
        cold[gbeg + i] = outd[i];
    }
}

// ---------------------------------------------------------------------------
// edge weight precompute: ex1[slot] = float4 of per-head exp(lrelu(as+ad))
// ---------------------------------------------------------------------------
__global__ void edge_w1_kernel(const int* __restrict__ col, const int* __restrict__ cold,
                               const float* __restrict__ as, const float* __restrict__ ad,
                               float4* __restrict__ ex)
{
    const int j = blockIdx.x * 256 + threadIdx.x;
    if (j >= NET) return;
    const int s = col[j], d = cold[j];
    const float4 a = ((const float4*)as)[s];
    const float4 b = ((const float4*)ad)[d];
    float4 v;
    v.x = __expf(lrelu(a.x + b.x));
    v.y = __expf(lrelu(a.y + b.y));
    v.z = __expf(lrelu(a.z + b.z));
    v.w = __expf(lrelu(a.w + b.w));
    ex[j] = v;
}

__global__ void edge_w2_kernel(const int* __restrict__ col, const int* __restrict__ cold,
                               const float* __restrict__ as, const float* __restrict__ ad,
                               float* __restrict__ ex)
{
    const int j = blockIdx.x * 256 + threadIdx.x;
    if (j >= NET) return;
    ex[j] = __expf(lrelu(as[col[j]] + ad[cold[j]]));
}

// ---------------------------------------------------------------------------
// Fused layer-1 tail v2: wave per dst (uniform via readfirstlane so col /
// row_ptr become s_load and addressing is saddr+voffset); weights come
// precomputed from ex1 (1 dword VMEM/edge, voffset=head*4). Inner-loop VALU
// = 2 cvt + 2 fma + 1 add per edge.
// ---------------------------------------------------------------------------
__global__ __launch_bounds__(256) void agg1_fused_kernel(
    const int* __restrict__ row_ptr, const int* __restrict__ col,
    const unsigned* __restrict__ hh, const float* __restrict__ exw,
    const float* __restrict__ b1, float* __restrict__ act)
{
    const int d    = __builtin_amdgcn_readfirstlane((blockIdx.x * 256 + threadIdx.x) >> 6);
    const int lane = threadIdx.x & 63;
    const int head = lane >> 4;
    const int beg = row_ptr[d], end = row_ptr[d + 1];   // s_load (d uniform)

    float acc0 = 0.f, acc1 = 0.f, den = 0.f;
    int j = beg;
    for (; j + 8 <= end; j += 8) {
        float    w[8];
        unsigned g[8];
#pragma unroll
        for (int k = 0; k < 8; k++) {
            const int s = col[j + k];                 // s_load (uniform)
            w[k] = exw[(j + k) * 4 + head];           // saddr + voffset(head*4)
            g[k] = hh[s * 64 + lane];                 // saddr + voffset(lane*4)
        }
#pragma unroll
        for (int k = 0; k < 8; k++) {
            const float2 g2 = unpk16(g[k]);
            den  += w[k];
            acc0 += w[k] * g2.x;
            acc1 += w[k] * g2.y;
        }
    }
    for (; j < end; j++) {
        const int s = col[j];
        const float w = exw[j * 4 + head];
        const float2 g2 = unpk16(hh[s * 64 + lane]);
        den  += w;
        acc0 += w * g2.x;
        acc1 += w * g2.y;
    }
    const float2 bb  = ((const float2*)b1)[lane];
    const float  inv = 1.f / (den + 1e-16f);
    float v0 = acc0 * inv + bb.x;
    float v1 = acc1 * inv + bb.y;
    v0 = v0 > 0.f ? v0 : (__expf(v0) - 1.f);
    v1 = v1 > 0.f ? v1 : (__expf(v1) - 1.f);
    ((float2*)act)[d * 64 + lane] = make_float2(v0, v1);
}

// ---------------------------------------------------------------------------
// Fused layer-2 tail v2: wave per dst, lane = channel; w is wave-uniform
// (s_load from ex2). Inner-loop VALU = 2 ops per edge.
// ---------------------------------------------------------------------------
__global__ __launch_bounds__(256) void agg2_fused_kernel(
    const int* __restrict__ row_ptr, const int* __restrict__ col,
    const float* __restrict__ h, const float* __restrict__ exw,
    const float* __restrict__ b2, float* __restrict__ out)
{
    const int d    = __builtin_amdgcn_readfirstlane((blockIdx.x * 256 + threadIdx.x) >> 6);
    const int lane = threadIdx.x & 63;
    const int beg = row_ptr[d], end = row_ptr[d + 1];

    float acc = 0.f, den = 0.f;
    int j = beg;
    for (; j + 8 <= end; j += 8) {
        float w[8], g[8];
#pragma unroll
        for (int k = 0; k < 8; k++) {
            const int s = col[j + k];                 // s_load
            w[k] = exw[j + k];                        // s_load (uniform)
            g[k] = h[s * 64 + lane];                  // saddr + voffset
        }
#pragma unroll
        for (int k = 0; k < 8; k++) {
            den += w[k];
            acc += w[k] * g[k];
        }
    }
    for (; j < end; j++) {
        const float w = exw[j];
        den += w;
        acc += w * h[col[j] * 64 + lane];
    }
    out[d * 64 + lane] = acc / (den + 1e-16f) + b2[lane];
}

// ---------------------------------------------------------------------------
extern "C" void kernel_launch(void* const* d_in, const int* in_sizes, int n_in,
                              void* d_out, int out_size, void* d_ws, size_t ws_size,
                              hipStream_t stream)
{
    const float* x    = (const float*)d_in[0];
    const int*   ei   = (const int*)  d_in[1];
    const float* W1   = (const float*)d_in[2];
    const float* at_s1= (const float*)d_in[3];
    const float* at_d1= (const float*)d_in[4];
    const float* b1   = (const float*)d_in[5];
    const float* W2   = (const float*)d_in[6];
    const float* at_s2= (const float*)d_in[7];
    const float* at_d2= (const float*)d_in[8];
    const float* b2   = (const float*)d_in[9];
    float*       out  = (float*)d_out;

    // workspace layout (~76 MB; harness ws proven >= ~98 MB in R1)
    float* fw   = (float*)d_ws;
    float* act1 = fw;                  // NN*128  fp32 (gemm2 input)
    float* h2   = act1 + NN * 128;     // NN*64   fp32
    float* as1  = h2   + NN * 64;      // NN*4
    float* ad1  = as1  + NN * 4;       // NN*4
    float* as2  = ad1  + NN * 4;       // NN
    float* ad2  = as2  + NN;           // NN
    float* ex1  = ad2  + NN;           // NET*4 (float4 per slot)
    float* ex2  = ex1  + (size_t)NET * 4;  // NET
    unsigned* hh = (unsigned*)(ex2 + NET); // NN*64 (fp16-packed h1)
    uint2* pairs = (uint2*)hh;             // NET uint2 — consumed before hh written
    int*   row_ptr = (int*)(hh + NN * 64); // NN+1
    int*   col     = row_ptr + NN + 1;     // NET
    int*   cold    = col  + NET;           // NET
    int*   bcnt    = cold + NET;           // 256 (zeroed)
    int*   boff    = bcnt + 256;           // 257
    int*   bcursor = boff + 257;           // 256

    hipMemsetAsync(bcnt, 0, 256 * sizeof(int), stream);

    const int eg1024 = (NET + 1023) / 1024;
    const int eg256  = (NET + 255) / 256;
    bcount_kernel<<<eg1024, 1024, 0, stream>>>(ei, bcnt);
    bscan_kernel <<<1, 256, 0, stream>>>(bcnt, boff, bcursor, row_ptr);
    bin_kernel   <<<eg1024, 1024, 0, stream>>>(ei, bcursor, pairs);
    bsort_kernel <<<NBUCK, 512, 0, stream>>>(boff, pairs, row_ptr, col, cold);

    const int gemm_grid = (NN + 63) / 64;
    const int node_wave_grid = NN / 4;   // 12500 blocks, exact (50000 waves)

    // layer 1
    gemm1_alpha_kernel<<<gemm_grid, 256, 0, stream>>>(x, W1, at_s1, at_d1, hh, as1, ad1);
    edge_w1_kernel    <<<eg256, 256, 0, stream>>>(col, cold, as1, ad1, (float4*)ex1);
    agg1_fused_kernel <<<node_wave_grid, 256, 0, stream>>>(row_ptr, col, hh, ex1, b1, act1);

    // layer 2
    gemm2_alpha_kernel<<<gemm_grid, 256, 0, stream>>>(act1, W2, at_s2, at_d2, h2, as2, ad2);
    edge_w2_kernel    <<<eg256, 256, 0, stream>>>(col, cold, as2, ad2, ex2);
    agg2_fused_kernel <<<node_wave_grid, 256, 0, stream>>>(row_ptr, col, h2, ex2, b2, out);
}

// Round 7
// 290.592 us; speedup vs baseline: 1.0726x; 1.0726x over previous
//
#include <hip/hip_runtime.h>

#define NN    50000      // nodes
#define NE    800000     // edges (without self loops)
#define NET   850000     // NE + NN (with self loops)
#define NBUCK ((NN + 255) / 256)   // 196 dst-buckets of 256 nodes
#define MAXB  8192       // LDS capacity per bucket (avg 4352, sigma 66)

typedef __fp16 half2_t __attribute__((ext_vector_type(2)));
typedef _Float16 half8 __attribute__((ext_vector_type(8)));
typedef float floatx4 __attribute__((ext_vector_type(4)));

__device__ __forceinline__ float lrelu(float v) { return fmaxf(v, 0.2f * v); }
__device__ __forceinline__ unsigned pk16(float a, float b) {
    half2_t h = __builtin_amdgcn_cvt_pkrtz(a, b);
    return __builtin_bit_cast(unsigned, h);
}
__device__ __forceinline__ float2 unpk16(unsigned u) {
    half2_t h = __builtin_bit_cast(half2_t, u);
    return make_float2((float)h.x, (float)h.y);
}

// ---------------------------------------------------------------------------
// prep: x -> fp16 (row-major), W1/W2 -> fp16 transposed [n][k]
// ---------------------------------------------------------------------------
__global__ void cvt_x_kernel(const float* __restrict__ x, _Float16* __restrict__ xh)
{
    const int i = blockIdx.x * 256 + threadIdx.x;   // < NN*128/4 exact
    const float4 v = ((const float4*)x)[i];
    ((uint2*)xh)[i] = make_uint2(pk16(v.x, v.y), pk16(v.z, v.w));
}

__global__ void prep_w_kernel(const float* __restrict__ W1, const float* __restrict__ W2,
                              _Float16* __restrict__ w1t, _Float16* __restrict__ w2t)
{
    const int idx = blockIdx.x * 256 + threadIdx.x;  // 96*256 = 24576 exact
    if (idx < 16384) {
        const int k = idx >> 7, n = idx & 127;
        w1t[n * 128 + k] = (_Float16)W1[idx];
    } else {
        const int j = idx - 16384;
        const int k = j >> 6, n = j & 63;
        w2t[n * 128 + k] = (_Float16)W2[j];
    }
}

// ---------------------------------------------------------------------------
// MFMA GEMM1: h1h[N,128 fp16] = xh[N,128] @ w1t^T   (w1t is [n][k])
// No LDS: wave = 16 rows x 128 cols, 4 K-steps x 8 N-tiles of 16x16x32.
// A frag: lane m=lane&15, k=(lane>>4)*8+j (16B contiguous from row-major xh).
// B frag: lane n=lane&15, k=(lane>>4)*8+j (16B contiguous from w1t[n][k]).
// C/D:    col=lane&15, row=(lane>>4)*4+reg.
// ---------------------------------------------------------------------------
__global__ __launch_bounds__(256) void gemm1_mfma_kernel(
    const _Float16* __restrict__ xh, const _Float16* __restrict__ w1t,
    _Float16* __restrict__ h1h)
{
    const int t    = threadIdx.x;
    const int lane = t & 63;
    const int m    = lane & 15;
    const int q    = lane >> 4;
    const int rbase = blockIdx.x * 64 + (t >> 6) * 16;   // wave's first row

    const int rme = rbase + m;
    const int rc  = rme < NN ? rme : NN - 1;
    const _Float16* ap = xh + rc * 128 + q * 8;

    floatx4 acc[8];
#pragma unroll
    for (int nt = 0; nt < 8; nt++) acc[nt] = (floatx4){0.f, 0.f, 0.f, 0.f};

#pragma unroll
    for (int ks = 0; ks < 4; ks++) {
        const half8 a = *(const half8*)(ap + ks * 32);
#pragma unroll
        for (int nt = 0; nt < 8; nt++) {
            const half8 b = *(const half8*)(w1t + (nt * 16 + m) * 128 + ks * 32 + q * 8);
            acc[nt] = __builtin_amdgcn_mfma_f32_16x16x32_f16(a, b, acc[nt], 0, 0, 0);
        }
    }

#pragma unroll
    for (int nt = 0; nt < 8; nt++) {
#pragma unroll
        for (int r = 0; r < 4; r++) {
            const int row = rbase + q * 4 + r;
            if (row < NN) h1h[row * 128 + nt * 16 + m] = (_Float16)acc[nt][r];
        }
    }
}

// ---------------------------------------------------------------------------
// MFMA GEMM2: h2h[N,64 fp16] = act1h[N,128] @ w2t^T
// ---------------------------------------------------------------------------
__global__ __launch_bounds__(256) void gemm2_mfma_kernel(
    const _Float16* __restrict__ ah, const _Float16* __restrict__ w2t,
    _Float16* __restrict__ h2h)
{
    const int t    = threadIdx.x;
    const int lane = t & 63;
    const int m    = lane & 15;
    const int q    = lane >> 4;
    const int rbase = blockIdx.x * 64 + (t >> 6) * 16;

    const int rme = rbase + m;
    const int rc  = rme < NN ? rme : NN - 1;
    const _Float16* ap = ah + rc * 128 + q * 8;

    floatx4 acc[4];
#pragma unroll
    for (int nt = 0; nt < 4; nt++) acc[nt] = (floatx4){0.f, 0.f, 0.f, 0.f};

#pragma unroll
    for (int ks = 0; ks < 4; ks++) {
        const half8 a = *(const half8*)(ap + ks * 32);
#pragma unroll
        for (int nt = 0; nt < 4; nt++) {
            const half8 b = *(const half8*)(w2t + (nt * 16 + m) * 128 + ks * 32 + q * 8);
            acc[nt] = __builtin_amdgcn_mfma_f32_16x16x32_f16(a, b, acc[nt], 0, 0, 0);
        }
    }

#pragma unroll
    for (int nt = 0; nt < 4; nt++) {
#pragma unroll
        for (int r = 0; r < 4; r++) {
            const int row = rbase + q * 4 + r;
            if (row < NN) h2h[row * 64 + nt * 16 + m] = (_Float16)acc[nt][r];
        }
    }
}

// ---------------------------------------------------------------------------
// alpha kernels (fp16 input)
// ---------------------------------------------------------------------------
__global__ void alpha1h_kernel(const _Float16* __restrict__ h,
                               const float* __restrict__ att_s,
                               const float* __restrict__ att_d,
                               float* __restrict__ as, float* __restrict__ ad)
{
    const int t    = threadIdx.x;
    const int node = blockIdx.x * 2 + (t >> 7);
    const int c    = t & 127;
    const float v  = (float)h[node * 128 + c];
    float ps = v * att_s[c];
    float pd = v * att_d[c];
#pragma unroll
    for (int off = 16; off > 0; off >>= 1) {
        ps += __shfl_down(ps, off, 32);
        pd += __shfl_down(pd, off, 32);
    }
    if ((c & 31) == 0) {
        as[node * 4 + (c >> 5)] = ps;
        ad[node * 4 + (c >> 5)] = pd;
    }
}

__global__ void alpha2h_kernel(const _Float16* __restrict__ h,
                               const float* __restrict__ att_s,
                               const float* __restrict__ att_d,
                               float* __restrict__ as, float* __restrict__ ad)
{
    const int t    = threadIdx.x;
    const int node = blockIdx.x * 4 + (t >> 6);
    const int c    = t & 63;
    const float v  = (float)h[node * 64 + c];
    float ps = v * att_s[c];
    float pd = v * att_d[c];
#pragma unroll
    for (int off = 32; off > 0; off >>= 1) {
        ps += __shfl_down(ps, off, 64);
        pd += __shfl_down(pd, off, 64);
    }
    if (c == 0) { as[node] = ps; ad[node] = pd; }
}

// ---------------------------------------------------------------------------
// CSR build v2 (verified R5/R6)
// ---------------------------------------------------------------------------
__global__ __launch_bounds__(1024) void bcount_kernel(const int* __restrict__ ei,
                                                      int* __restrict__ bcnt)
{
    __shared__ int lh[NBUCK];
    const int t = threadIdx.x;
    if (t < NBUCK) lh[t] = 0;
    __syncthreads();
    const int e = blockIdx.x * 1024 + t;
    if (e < NET) {
        const int d = (e < NE) ? ei[NE + e] : e - NE;
        atomicAdd(&lh[d >> 8], 1);
    }
    __syncthreads();
    if (t < NBUCK && lh[t]) atomicAdd(&bcnt[t], lh[t]);
}

__global__ __launch_bounds__(256) void bscan_kernel(const int* __restrict__ bcnt,
                                                    int* __restrict__ boff,
                                                    int* __restrict__ bcursor,
                                                    int* __restrict__ row_ptr)
{
    __shared__ int sh[256];
    const int t = threadIdx.x;
    const int v = (t < NBUCK) ? bcnt[t] : 0;
    sh[t] = v;
    __syncthreads();
#pragma unroll
    for (int off = 1; off < 256; off <<= 1) {
        int u = (t >= off) ? sh[t - off] : 0;
        __syncthreads();
        sh[t] += u;
        __syncthreads();
    }
    if (t < NBUCK) {
        const int ex = sh[t] - v;
        boff[t]    = ex;
        bcursor[t] = ex;
    }
    if (t == 0) { boff[NBUCK] = NET; row_ptr[NN] = NET; }
}

__global__ __launch_bounds__(1024) void bin_kernel(const int* __restrict__ ei,
                                                   int* __restrict__ bcursor,
                                                   uint2* __restrict__ pairs)
{
    __shared__ int hist[NBUCK], base[NBUCK], cur[NBUCK];
    const int t = threadIdx.x;
    if (t < NBUCK) { hist[t] = 0; cur[t] = 0; }
    __syncthreads();
    const int e = blockIdx.x * 1024 + t;
    int s = 0, d = 0, bk = 0;
    const bool ok = e < NET;
    if (ok) {
        if (e < NE) { s = ei[e]; d = ei[NE + e]; } else { s = d = e - NE; }
        bk = d >> 8;
        atomicAdd(&hist[bk], 1);
    }
    __syncthreads();
    if (t < NBUCK && hist[t]) base[t] = atomicAdd(&bcursor[t], hist[t]);
    __syncthreads();
    if (ok) {
        const int r = atomicAdd(&cur[bk], 1);
        pairs[base[bk] + r] = make_uint2((unsigned)s, (unsigned)d);
    }
}

__global__ __launch_bounds__(512) void bsort_kernel(const int* __restrict__ boff,
                                                    const uint2* __restrict__ pairs,
                                                    int* __restrict__ row_ptr,
                                                    int* __restrict__ col,
                                                    int* __restrict__ cold)
{
    __shared__ int hist[256], cur[256], sh[256];
    __shared__ int outl[MAXB];
    __shared__ int outd[MAXB];
    const int b = blockIdx.x, t = threadIdx.x;
    const int gbeg = boff[b], gend = boff[b + 1];
    const int m = gend - gbeg;
    if (t < 256) hist[t] = 0;
    __syncthreads();
    for (int i = t; i < m; i += 512)
        atomicAdd(&hist[pairs[gbeg + i].y & 255], 1);
    __syncthreads();
    if (t < 256) sh[t] = hist[t];
    __syncthreads();
#pragma unroll
    for (int off = 1; off < 256; off <<= 1) {
        int u = (t < 256 && t >= off) ? sh[t - off] : 0;
        __syncthreads();
        if (t < 256) sh[t] += u;
        __syncthreads();
    }
    if (t < 256) {
        const int ex = sh[t] - hist[t];
        cur[t] = ex;
        const int node = (b << 8) + t;
        if (node < NN) row_ptr[node] = gbeg + ex;
    }
    __syncthreads();
    for (int i = t; i < m; i += 512) {
        const uint2 p = pairs[gbeg + i];
        const int r = atomicAdd(&cur[p.y & 255], 1);
        outl[r] = (int)p.x;
        outd[r] = (int)p.y;
    }
    __syncthreads();
    for (int i = t; i < m; i += 512) {
        col[gbeg + i]  = outl[i];
        cold[gbeg + i] = outd[i];
    }
}

// ---------------------------------------------------------------------------
// edge weight precompute (unchanged, verified R6)
// ---------------------------------------------------------------------------
__global__ void edge_w1_kernel(const int* __restrict__ col, const int* __restrict__ cold,
                               const float* __restrict__ as, const float* __restrict__ ad,
                               float4* __restrict__ ex)
{
    const int j = blockIdx.x * 256 + threadIdx.x;
    if (j >= NET) return;
    const int s = col[j], d = cold[j];
    const float4 a = ((const float4*)as)[s];
    const float4 b = ((const float4*)ad)[d];
    float4 v;
    v.x = __expf(lrelu(a.x + b.x));
    v.y = __expf(lrelu(a.y + b.y));
    v.z = __expf(lrelu(a.z + b.z));
    v.w = __expf(lrelu(a.w + b.w));
    ex[j] = v;
}

__global__ void edge_w2_kernel(const int* __restrict__ col, const int* __restrict__ cold,
                               const float* __restrict__ as, const float* __restrict__ ad,
                               float* __restrict__ ex)
{
    const int j = blockIdx.x * 256 + threadIdx.x;
    if (j >= NET) return;
    ex[j] = __expf(lrelu(as[col[j]] + ad[cold[j]]));
}

// ---------------------------------------------------------------------------
// Fused layer-1 tail (verified R6): scalarized addressing, precomputed w.
// Epilogue now writes act1h fp16-packed (gemm2 MFMA input).
// ---------------------------------------------------------------------------
__global__ __launch_bounds__(256) void agg1_fused_kernel(
    const int* __restrict__ row_ptr, const int* __restrict__ col,
    const unsigned* __restrict__ hh, const float* __restrict__ exw,
    const float* __restrict__ b1, unsigned* __restrict__ acth)
{
    const int d    = __builtin_amdgcn_readfirstlane((blockIdx.x * 256 + threadIdx.x) >> 6);
    const int lane = threadIdx.x & 63;
    const int head = lane >> 4;
    const int beg = row_ptr[d], end = row_ptr[d + 1];   // s_load (d uniform)

    float acc0 = 0.f, acc1 = 0.f, den = 0.f;
    int j = beg;
    for (; j + 8 <= end; j += 8) {
        float    w[8];
        unsigned g[8];
#pragma unroll
        for (int k = 0; k < 8; k++) {
            const int s = col[j + k];                 // s_load (uniform)
            w[k] = exw[(j + k) * 4 + head];           // saddr + voffset(head*4)
            g[k] = hh[s * 64 + lane];                 // saddr + voffset(lane*4)
        }
#pragma unroll
        for (int k = 0; k < 8; k++) {
            const float2 g2 = unpk16(g[k]);
            den  += w[k];
            acc0 += w[k] * g2.x;
            acc1 += w[k] * g2.y;
        }
    }
    for (; j < end; j++) {
        const int s = col[j];
        const float w = exw[j * 4 + head];
        const float2 g2 = unpk16(hh[s * 64 + lane]);
        den  += w;
        acc0 += w * g2.x;
        acc1 += w * g2.y;
    }
    const float2 bb  = ((const float2*)b1)[lane];
    const float  inv = 1.f / (den + 1e-16f);
    float v0 = acc0 * inv + bb.x;
    float v1 = acc1 * inv + bb.y;
    v0 = v0 > 0.f ? v0 : (__expf(v0) - 1.f);
    v1 = v1 > 0.f ? v1 : (__expf(v1) - 1.f);
    acth[d * 64 + lane] = pk16(v0, v1);
}

// ---------------------------------------------------------------------------
// Fused layer-2 tail (verified R6) with fp16 h2 gathers.
// ---------------------------------------------------------------------------
__global__ __launch_bounds__(256) void agg2_fused_kernel(
    const int* __restrict__ row_ptr, const int* __restrict__ col,
    const _Float16* __restrict__ h, const float* __restrict__ exw,
    const float* __restrict__ b2, float* __restrict__ out)
{
    const int d    = __builtin_amdgcn_readfirstlane((blockIdx.x * 256 + threadIdx.x) >> 6);
    const int lane = threadIdx.x & 63;
    const int beg = row_ptr[d], end = row_ptr[d + 1];

    float acc = 0.f, den = 0.f;
    int j = beg;
    for (; j + 8 <= end; j += 8) {
        float w[8], g[8];
#pragma unroll
        for (int k = 0; k < 8; k++) {
            const int s = col[j + k];                 // s_load
            w[k] = exw[j + k];                        // s_load (uniform)
            g[k] = (float)h[s * 64 + lane];           // saddr + voffset
        }
#pragma unroll
        for (int k = 0; k < 8; k++) {
            den += w[k];
            acc += w[k] * g[k];
        }
    }
    for (; j < end; j++) {
        const float w = exw[j];
        den += w;
        acc += w * (float)h[col[j] * 64 + lane];
    }
    out[d * 64 + lane] = acc / (den + 1e-16f) + b2[lane];
}

// ---------------------------------------------------------------------------
extern "C" void kernel_launch(void* const* d_in, const int* in_sizes, int n_in,
                              void* d_out, int out_size, void* d_ws, size_t ws_size,
                              hipStream_t stream)
{
    const float* x    = (const float*)d_in[0];
    const int*   ei   = (const int*)  d_in[1];
    const float* W1   = (const float*)d_in[2];
    const float* at_s1= (const float*)d_in[3];
    const float* at_d1= (const float*)d_in[4];
    const float* b1   = (const float*)d_in[5];
    const float* W2   = (const float*)d_in[6];
    const float* at_s2= (const float*)d_in[7];
    const float* at_d2= (const float*)d_in[8];
    const float* b2   = (const float*)d_in[9];
    float*       out  = (float*)d_out;

    // workspace layout (~72 MB)
    float* fw   = (float*)d_ws;
    float* as1  = fw;                  // NN*4
    float* ad1  = as1  + NN * 4;       // NN*4
    float* as2  = ad1  + NN * 4;       // NN
    float* ad2  = as2  + NN;           // NN
    float* ex1  = ad2  + NN;           // NET*4 (float4 per slot)
    float* ex2  = ex1  + (size_t)NET * 4;  // NET
    _Float16* xh    = (_Float16*)(ex2 + NET); // NN*128
    _Float16* h1h   = xh   + (size_t)NN * 128; // NN*128
    _Float16* act1h = h1h  + (size_t)NN * 128; // NN*128
    _Float16* h2h   = act1h+ (size_t)NN * 128; // NN*64
    _Float16* w1t   = h2h  + (size_t)NN * 64;  // 16384
    _Float16* w2t   = w1t  + 16384;            // 8192
    int*   row_ptr = (int*)(w2t + 8192);       // NN+1
    int*   col     = row_ptr + NN + 1;         // NET
    int*   cold    = col  + NET;               // NET
    int*   bcnt    = cold + NET;               // 256 (zeroed)
    int*   boff    = bcnt + 256;               // 257
    int*   bcursor = boff + 257;               // 256
    uint2* pairs   = (uint2*)xh;               // NET uint2 — dead before cvt_x runs

    hipMemsetAsync(bcnt, 0, 256 * sizeof(int), stream);

    const int eg1024 = (NET + 1023) / 1024;
    const int eg256  = (NET + 255) / 256;
    // CSR build first (pairs aliases xh; cvt_x runs after bsort)
    bcount_kernel<<<eg1024, 1024, 0, stream>>>(ei, bcnt);
    bscan_kernel <<<1, 256, 0, stream>>>(bcnt, boff, bcursor, row_ptr);
    bin_kernel   <<<eg1024, 1024, 0, stream>>>(ei, bcursor, pairs);
    bsort_kernel <<<NBUCK, 512, 0, stream>>>(boff, pairs, row_ptr, col, cold);

    cvt_x_kernel <<<NN * 128 / 4 / 256, 256, 0, stream>>>(x, xh);
    prep_w_kernel<<<96, 256, 0, stream>>>(W1, W2, w1t, w2t);

    const int gemm_grid = (NN + 63) / 64;   // 782
    const int node_wave_grid = NN / 4;      // 12500 blocks (wave per node)

    // layer 1
    gemm1_mfma_kernel<<<gemm_grid, 256, 0, stream>>>(xh, w1t, h1h);
    alpha1h_kernel   <<<NN / 2, 256, 0, stream>>>(h1h, at_s1, at_d1, as1, ad1);
    edge_w1_kernel   <<<eg256, 256, 0, stream>>>(col, cold, as1, ad1, (float4*)ex1);
    agg1_fused_kernel<<<node_wave_grid, 256, 0, stream>>>(row_ptr, col,
                        (const unsigned*)h1h, ex1, b1, (unsigned*)act1h);

    // layer 2
    gemm2_mfma_kernel<<<gemm_grid, 256, 0, stream>>>(act1h, w2t, h2h);
    alpha2h_kernel   <<<NN / 4, 256, 0, stream>>>(h2h, at_s2, at_d2, as2, ad2);
    edge_w2_kernel   <<<eg256, 256, 0, stream>>>(col, cold, as2, ad2, ex2);
    agg2_fused_kernel<<<node_wave_grid, 256, 0, stream>>>(row_ptr, col, h2h, ex2, b2, out);
}

// Round 8
// 273.828 us; speedup vs baseline: 1.1383x; 1.0612x over previous
//
#include <hip/hip_runtime.h>

#define NN    50000      // nodes
#define NE    800000     // edges (without self loops)
#define NET   850000     // NE + NN (with self loops)
#define NBUCK ((NN + 255) / 256)   // 196 dst-buckets of 256 nodes
#define MAXB  8192       // LDS capacity per bucket (avg 4352, sigma 66)

typedef __fp16 half2_t __attribute__((ext_vector_type(2)));
typedef _Float16 half8 __attribute__((ext_vector_type(8)));
typedef float floatx4 __attribute__((ext_vector_type(4)));

__device__ __forceinline__ float lrelu(float v) { return fmaxf(v, 0.2f * v); }
__device__ __forceinline__ unsigned pk16(float a, float b) {
    half2_t h = __builtin_amdgcn_cvt_pkrtz(a, b);
    return __builtin_bit_cast(unsigned, h);
}
__device__ __forceinline__ float2 unpk16(unsigned u) {
    half2_t h = __builtin_bit_cast(half2_t, u);
    return make_float2((float)h.x, (float)h.y);
}

// ---------------------------------------------------------------------------
// prep: x -> fp16 row-major; W1/W2 -> fp16 transposed [n][k]. One kernel.
// ---------------------------------------------------------------------------
__global__ void prep_kernel(const float* __restrict__ x,
                            const float* __restrict__ W1, const float* __restrict__ W2,
                            _Float16* __restrict__ xh,
                            _Float16* __restrict__ w1t, _Float16* __restrict__ w2t)
{
    const int b = blockIdx.x;
    if (b < NN * 128 / 4 / 256) {
        const int i = b * 256 + threadIdx.x;
        const float4 v = ((const float4*)x)[i];
        ((uint2*)xh)[i] = make_uint2(pk16(v.x, v.y), pk16(v.z, v.w));
    } else {
        const int idx = (b - NN * 128 / 4 / 256) * 256 + threadIdx.x;  // < 24576
        if (idx < 16384) {
            const int k = idx >> 7, n = idx & 127;
            w1t[n * 128 + k] = (_Float16)W1[idx];
        } else {
            const int j = idx - 16384;
            const int k = j >> 6, n = j & 63;
            w2t[n * 128 + k] = (_Float16)W2[j];
        }
    }
}

// ---------------------------------------------------------------------------
// MFMA GEMM1 + alpha1: h1h[N,128 fp16] = xh @ w1t^T; as/ad via LDS dot.
// Wave = 16 rows x 128 cols (16x16x32 MFMA, layouts verified R7).
// Epilogue: C tile -> LDS fp16 -> coalesced half8 global write + per-(row,
// head) dot with att vectors (thread t: row=t>>2, head=t&3).
// ---------------------------------------------------------------------------
__global__ __launch_bounds__(256) void gemm1_mfma_kernel(
    const _Float16* __restrict__ xh, const _Float16* __restrict__ w1t,
    const float* __restrict__ att_s, const float* __restrict__ att_d,
    _Float16* __restrict__ h1h, float* __restrict__ as, float* __restrict__ ad)
{
    __shared__ _Float16 hs[64 * 128];   // 16 KB
    const int t    = threadIdx.x;
    const int lane = t & 63;
    const int m    = lane & 15;
    const int q    = lane >> 4;
    const int wv   = t >> 6;
    const int gr0  = blockIdx.x * 64;
    const int rbase = gr0 + wv * 16;

    const int rme = rbase + m;
    const int rc  = rme < NN ? rme : NN - 1;
    const _Float16* ap = xh + (size_t)rc * 128 + q * 8;

    floatx4 acc[8];
#pragma unroll
    for (int nt = 0; nt < 8; nt++) acc[nt] = (floatx4){0.f, 0.f, 0.f, 0.f};

#pragma unroll
    for (int ks = 0; ks < 4; ks++) {
        const half8 a = *(const half8*)(ap + ks * 32);
#pragma unroll
        for (int nt = 0; nt < 8; nt++) {
            const half8 b = *(const half8*)(w1t + (nt * 16 + m) * 128 + ks * 32 + q * 8);
            acc[nt] = __builtin_amdgcn_mfma_f32_16x16x32_f16(a, b, acc[nt], 0, 0, 0);
        }
    }

    // stage C tile to LDS (fp16)
    const int lrow0 = wv * 16 + q * 4;
#pragma unroll
    for (int nt = 0; nt < 8; nt++)
#pragma unroll
        for (int r = 0; r < 4; r++)
            hs[(lrow0 + r) * 128 + nt * 16 + m] = (_Float16)acc[nt][r];
    __syncthreads();

    // coalesced h1h write: 1024 half8 per block
#pragma unroll
    for (int i = t; i < 1024; i += 256) {
        const int row = i >> 4;
        if (gr0 + row < NN)
            ((half8*)h1h)[(size_t)(gr0 + row) * 16 + (i & 15)] = ((const half8*)hs)[i];
    }

    // alpha: thread t -> row t>>2, head t&3 (32 channels)
    const int arow = t >> 2, hd = t & 3;
    const int grow = gr0 + arow;
    float ps = 0.f, pd = 0.f;
    const half8*  hp8 = (const half8*)(hs + arow * 128 + hd * 32);
    const float4* s4  = (const float4*)(att_s + hd * 32);
    const float4* d4  = (const float4*)(att_d + hd * 32);
#pragma unroll
    for (int cc = 0; cc < 4; cc++) {
        const half8 hv = hp8[cc];
        const float4 a = s4[cc * 2], b = s4[cc * 2 + 1];
        const float4 c = d4[cc * 2], e = d4[cc * 2 + 1];
        ps += (float)hv[0]*a.x + (float)hv[1]*a.y + (float)hv[2]*a.z + (float)hv[3]*a.w
            + (float)hv[4]*b.x + (float)hv[5]*b.y + (float)hv[6]*b.z + (float)hv[7]*b.w;
        pd += (float)hv[0]*c.x + (float)hv[1]*c.y + (float)hv[2]*c.z + (float)hv[3]*c.w
            + (float)hv[4]*e.x + (float)hv[5]*e.y + (float)hv[6]*e.z + (float)hv[7]*e.w;
    }
    if (grow < NN) {
        as[grow * 4 + hd] = ps;
        ad[grow * 4 + hd] = pd;
    }
}

// ---------------------------------------------------------------------------
// MFMA GEMM2 + alpha2: h2h[N,64 fp16] = act1h @ w2t^T; scalar as2/ad2.
// ---------------------------------------------------------------------------
__global__ __launch_bounds__(256) void gemm2_mfma_kernel(
    const _Float16* __restrict__ ah, const _Float16* __restrict__ w2t,
    const float* __restrict__ att_s, const float* __restrict__ att_d,
    _Float16* __restrict__ h2h, float* __restrict__ as, float* __restrict__ ad)
{
    __shared__ _Float16 hs[64 * 64];    // 8 KB
    const int t    = threadIdx.x;
    const int lane = t & 63;
    const int m    = lane & 15;
    const int q    = lane >> 4;
    const int wv   = t >> 6;
    const int gr0  = blockIdx.x * 64;
    const int rbase = gr0 + wv * 16;

    const int rme = rbase + m;
    const int rc  = rme < NN ? rme : NN - 1;
    const _Float16* ap = ah + (size_t)rc * 128 + q * 8;

    floatx4 acc[4];
#pragma unroll
    for (int nt = 0; nt < 4; nt++) acc[nt] = (floatx4){0.f, 0.f, 0.f, 0.f};

#pragma unroll
    for (int ks = 0; ks < 4; ks++) {
        const half8 a = *(const half8*)(ap + ks * 32);
#pragma unroll
        for (int nt = 0; nt < 4; nt++) {
            const half8 b = *(const half8*)(w2t + (nt * 16 + m) * 128 + ks * 32 + q * 8);
            acc[nt] = __builtin_amdgcn_mfma_f32_16x16x32_f16(a, b, acc[nt], 0, 0, 0);
        }
    }

    const int lrow0 = wv * 16 + q * 4;
#pragma unroll
    for (int nt = 0; nt < 4; nt++)
#pragma unroll
        for (int r = 0; r < 4; r++)
            hs[(lrow0 + r) * 64 + nt * 16 + m] = (_Float16)acc[nt][r];
    __syncthreads();

    // coalesced h2h write: 512 half8 per block
#pragma unroll
    for (int i = t; i < 512; i += 256) {
        const int row = i >> 3;
        if (gr0 + row < NN)
            ((half8*)h2h)[(size_t)(gr0 + row) * 8 + (i & 7)] = ((const half8*)hs)[i];
    }

    // alpha: thread t -> row t>>2, segment t&3 (16 channels); 4-lane reduce
    const int arow = t >> 2, sg = t & 3;
    const int grow = gr0 + arow;
    float ps = 0.f, pd = 0.f;
    const half8*  hp8 = (const half8*)(hs + arow * 64 + sg * 16);
    const float4* s4  = (const float4*)(att_s + sg * 16);
    const float4* d4  = (const float4*)(att_d + sg * 16);
#pragma unroll
    for (int cc = 0; cc < 2; cc++) {
        const half8 hv = hp8[cc];
        const float4 a = s4[cc * 2], b = s4[cc * 2 + 1];
        const float4 c = d4[cc * 2], e = d4[cc * 2 + 1];
        ps += (float)hv[0]*a.x + (float)hv[1]*a.y + (float)hv[2]*a.z + (float)hv[3]*a.w
            + (float)hv[4]*b.x + (float)hv[5]*b.y + (float)hv[6]*b.z + (float)hv[7]*b.w;
        pd += (float)hv[0]*c.x + (float)hv[1]*c.y + (float)hv[2]*c.z + (float)hv[3]*c.w
            + (float)hv[4]*e.x + (float)hv[5]*e.y + (float)hv[6]*e.z + (float)hv[7]*e.w;
    }
    ps += __shfl_down(ps, 2);  pd += __shfl_down(pd, 2);
    ps += __shfl_down(ps, 1);  pd += __shfl_down(pd, 1);
    if (sg == 0 && grow < NN) { as[grow] = ps; ad[grow] = pd; }
}

// ---------------------------------------------------------------------------
// CSR build v2 (verified R5/R6)
// ---------------------------------------------------------------------------
__global__ __launch_bounds__(1024) void bcount_kernel(const int* __restrict__ ei,
                                                      int* __restrict__ bcnt)
{
    __shared__ int lh[NBUCK];
    const int t = threadIdx.x;
    if (t < NBUCK) lh[t] = 0;
    __syncthreads();
    const int e = blockIdx.x * 1024 + t;
    if (e < NET) {
        const int d = (e < NE) ? ei[NE + e] : e - NE;
        atomicAdd(&lh[d >> 8], 1);
    }
    __syncthreads();
    if (t < NBUCK && lh[t]) atomicAdd(&bcnt[t], lh[t]);
}

__global__ __launch_bounds__(256) void bscan_kernel(const int* __restrict__ bcnt,
                                                    int* __restrict__ boff,
                                                    int* __restrict__ bcursor,
                                                    int* __restrict__ row_ptr)
{
    __shared__ int sh[256];
    const int t = threadIdx.x;
    const int v = (t < NBUCK) ? bcnt[t] : 0;
    sh[t] = v;
    __syncthreads();
#pragma unroll
    for (int off = 1; off < 256; off <<= 1) {
        int u = (t >= off) ? sh[t - off] : 0;
        __syncthreads();
        sh[t] += u;
        __syncthreads();
    }
    if (t < NBUCK) {
        const int ex = sh[t] - v;
        boff[t]    = ex;
        bcursor[t] = ex;
    }
    if (t == 0) { boff[NBUCK] = NET; row_ptr[NN] = NET; }
}

__global__ __launch_bounds__(1024) void bin_kernel(const int* __restrict__ ei,
                                                   int* __restrict__ bcursor,
                                                   uint2* __restrict__ pairs)
{
    __shared__ int hist[NBUCK], base[NBUCK], cur[NBUCK];
    const int t = threadIdx.x;
    if (t < NBUCK) { hist[t] = 0; cur[t] = 0; }
    __syncthreads();
    const int e = blockIdx.x * 1024 + t;
    int s = 0, d = 0, bk = 0;
    const bool ok = e < NET;
    if (ok) {
        if (e < NE) { s = ei[e]; d = ei[NE + e]; } else { s = d = e - NE; }
        bk = d >> 8;
        atomicAdd(&hist[bk], 1);
    }
    __syncthreads();
    if (t < NBUCK && hist[t]) base[t] = atomicAdd(&bcursor[t], hist[t]);
    __syncthreads();
    if (ok) {
        const int r = atomicAdd(&cur[bk], 1);
        pairs[base[bk] + r] = make_uint2((unsigned)s, (unsigned)d);
    }
}

__global__ __launch_bounds__(512) void bsort_kernel(const int* __restrict__ boff,
                                                    const uint2* __restrict__ pairs,
                                                    int* __restrict__ row_ptr,
                                                    int* __restrict__ col,
                                                    int* __restrict__ cold)
{
    __shared__ int hist[256], cur[256], sh[256];
    __shared__ int outl[MAXB];
    __shared__ int outd[MAXB];
    const int b = blockIdx.x, t = threadIdx.x;
    const int gbeg = boff[b], gend = boff[b + 1];
    const int m = gend - gbeg;
    if (t < 256) hist[t] = 0;
    __syncthreads();
    for (int i = t; i < m; i += 512)
        atomicAdd(&hist[pairs[gbeg + i].y & 255], 1);
    __syncthreads();
    if (t < 256) sh[t] = hist[t];
    __syncthreads();
#pragma unroll
    for (int off = 1; off < 256; off <<= 1) {
        int u = (t < 256 && t >= off) ? sh[t - off] : 0;
        __syncthreads();
        if (t < 256) sh[t] += u;
        __syncthreads();
    }
    if (t < 256) {
        const int ex = sh[t] - hist[t];
        cur[t] = ex;
        const int node = (b << 8) + t;
        if (node < NN) row_ptr[node] = gbeg + ex;
    }
    __syncthreads();
    for (int i = t; i < m; i += 512) {
        const uint2 p = pairs[gbeg + i];
        const int r = atomicAdd(&cur[p.y & 255], 1);
        outl[r] = (int)p.x;
        outd[r] = (int)p.y;
    }
    __syncthreads();
    for (int i = t; i < m; i += 512) {
        col[gbeg + i]  = outl[i];
        cold[gbeg + i] = outd[i];
    }
}

// ---------------------------------------------------------------------------
// edge weight precompute (unchanged, verified R6)
// ---------------------------------------------------------------------------
__global__ void edge_w1_kernel(const int* __restrict__ col, const int* __restrict__ cold,
                               const float* __restrict__ as, const float* __restrict__ ad,
                               float4* __restrict__ ex)
{
    const int j = blockIdx.x * 256 + threadIdx.x;
    if (j >= NET) return;
    const int s = col[j], d = cold[j];
    const float4 a = ((const float4*)as)[s];
    const float4 b = ((const float4*)ad)[d];
    float4 v;
    v.x = __expf(lrelu(a.x + b.x));
    v.y = __expf(lrelu(a.y + b.y));
    v.z = __expf(lrelu(a.z + b.z));
    v.w = __expf(lrelu(a.w + b.w));
    ex[j] = v;
}

__global__ void edge_w2_kernel(const int* __restrict__ col, const int* __restrict__ cold,
                               const float* __restrict__ as, const float* __restrict__ ad,
                               float* __restrict__ ex)
{
    const int j = blockIdx.x * 256 + threadIdx.x;
    if (j >= NET) return;
    ex[j] = __expf(lrelu(as[col[j]] + ad[cold[j]]));
}

// ---------------------------------------------------------------------------
// Fused layer-1 tail (verified R6/R7): scalarized addressing, precomputed w.
// Unroll 16 (32 outstanding VMEM). Writes act1h fp16-packed.
// ---------------------------------------------------------------------------
__global__ __launch_bounds__(256) void agg1_fused_kernel(
    const int* __restrict__ row_ptr, const int* __restrict__ col,
    const unsigned* __restrict__ hh, const float* __restrict__ exw,
    const float* __restrict__ b1, unsigned* __restrict__ acth)
{
    const int d    = __builtin_amdgcn_readfirstlane((blockIdx.x * 256 + threadIdx.x) >> 6);
    const int lane = threadIdx.x & 63;
    const int head = lane >> 4;
    const int beg = row_ptr[d], end = row_ptr[d + 1];   // s_load (d uniform)

    float acc0 = 0.f, acc1 = 0.f, den = 0.f;
    int j = beg;
    for (; j + 16 <= end; j += 16) {
        float    w[16];
        unsigned g[16];
#pragma unroll
        for (int k = 0; k < 16; k++) {
            const int s = col[j + k];
            w[k] = exw[(j + k) * 4 + head];
            g[k] = hh[s * 64 + lane];
        }
#pragma unroll
        for (int k = 0; k < 16; k++) {
            const float2 g2 = unpk16(g[k]);
            den  += w[k];
            acc0 += w[k] * g2.x;
            acc1 += w[k] * g2.y;
        }
    }
    for (; j + 4 <= end; j += 4) {
        float    w[4];
        unsigned g[4];
#pragma unroll
        for (int k = 0; k < 4; k++) {
            const int s = col[j + k];
            w[k] = exw[(j + k) * 4 + head];
            g[k] = hh[s * 64 + lane];
        }
#pragma unroll
        for (int k = 0; k < 4; k++) {
            const float2 g2 = unpk16(g[k]);
            den  += w[k];
            acc0 += w[k] * g2.x;
            acc1 += w[k] * g2.y;
        }
    }
    for (; j < end; j++) {
        const float w = exw[j * 4 + head];
        const float2 g2 = unpk16(hh[col[j] * 64 + lane]);
        den  += w;
        acc0 += w * g2.x;
        acc1 += w * g2.y;
    }
    const float2 bb  = ((const float2*)b1)[lane];
    const float  inv = 1.f / (den + 1e-16f);
    float v0 = acc0 * inv + bb.x;
    float v1 = acc1 * inv + bb.y;
    v0 = v0 > 0.f ? v0 : (__expf(v0) - 1.f);
    v1 = v1 > 0.f ? v1 : (__expf(v1) - 1.f);
    acth[d * 64 + lane] = pk16(v0, v1);
}

// ---------------------------------------------------------------------------
// Fused layer-2 tail (verified R6/R7), unroll 16, fp16 gathers.
// ---------------------------------------------------------------------------
__global__ __launch_bounds__(256) void agg2_fused_kernel(
    const int* __restrict__ row_ptr, const int* __restrict__ col,
    const _Float16* __restrict__ h, const float* __restrict__ exw,
    const float* __restrict__ b2, float* __restrict__ out)
{
    const int d    = __builtin_amdgcn_readfirstlane((blockIdx.x * 256 + threadIdx.x) >> 6);
    const int lane = threadIdx.x & 63;
    const int beg = row_ptr[d], end = row_ptr[d + 1];

    float acc = 0.f, den = 0.f;
    int j = beg;
    for (; j + 16 <= end; j += 16) {
        float w[16], g[16];
#pragma unroll
        for (int k = 0; k < 16; k++) {
            const int s = col[j + k];
            w[k] = exw[j + k];
            g[k] = (float)h[s * 64 + lane];
        }
#pragma unroll
        for (int k = 0; k < 16; k++) {
            den += w[k];
            acc += w[k] * g[k];
        }
    }
    for (; j + 4 <= end; j += 4) {
        float w[4], g[4];
#pragma unroll
        for (int k = 0; k < 4; k++) {
            const int s = col[j + k];
            w[k] = exw[j + k];
            g[k] = (float)h[s * 64 + lane];
        }
#pragma unroll
        for (int k = 0; k < 4; k++) {
            den += w[k];
            acc += w[k] * g[k];
        }
    }
    for (; j < end; j++) {
        const float w = exw[j];
        den += w;
        acc += w * (float)h[col[j] * 64 + lane];
    }
    out[d * 64 + lane] = acc / (den + 1e-16f) + b2[lane];
}

// ---------------------------------------------------------------------------
extern "C" void kernel_launch(void* const* d_in, const int* in_sizes, int n_in,
                              void* d_out, int out_size, void* d_ws, size_t ws_size,
                              hipStream_t stream)
{
    const float* x    = (const float*)d_in[0];
    const int*   ei   = (const int*)  d_in[1];
    const float* W1   = (const float*)d_in[2];
    const float* at_s1= (const float*)d_in[3];
    const float* at_d1= (const float*)d_in[4];
    const float* b1   = (const float*)d_in[5];
    const float* W2   = (const float*)d_in[6];
    const float* at_s2= (const float*)d_in[7];
    const float* at_d2= (const float*)d_in[8];
    const float* b2   = (const float*)d_in[9];
    float*       out  = (float*)d_out;

    // workspace layout (~80 MB, no aliasing)
    float* fw   = (float*)d_ws;
    float* as1  = fw;                  // NN*4
    float* ad1  = as1  + NN * 4;       // NN*4
    float* as2  = ad1  + NN * 4;       // NN
    float* ad2  = as2  + NN;           // NN
    float* ex1  = ad2  + NN;           // NET*4 (float4 per slot)
    float* ex2  = ex1  + (size_t)NET * 4;  // NET
    _Float16* xh    = (_Float16*)(ex2 + NET); // NN*128
    _Float16* h1h   = xh   + (size_t)NN * 128; // NN*128
    _Float16* act1h = h1h  + (size_t)NN * 128; // NN*128
    _Float16* h2h   = act1h+ (size_t)NN * 128; // NN*64
    _Float16* w1t   = h2h  + (size_t)NN * 64;  // 16384
    _Float16* w2t   = w1t  + 16384;            // 8192
    int*   row_ptr = (int*)(w2t + 8192);       // NN+1
    int*   col     = row_ptr + NN + 1;         // NET
    int*   cold    = col  + NET;               // NET
    int*   bcnt    = cold + NET;               // 256 (zeroed)
    int*   boff    = bcnt + 256;               // 257
    int*   bcursor = boff + 257;               // 256
    uint2* pairs   = (uint2*)(bcursor + 256);  // NET uint2

    hipMemsetAsync(bcnt, 0, 256 * sizeof(int), stream);

    const int eg1024 = (NET + 1023) / 1024;
    const int eg256  = (NET + 255) / 256;
    bcount_kernel<<<eg1024, 1024, 0, stream>>>(ei, bcnt);
    bscan_kernel <<<1, 256, 0, stream>>>(bcnt, boff, bcursor, row_ptr);
    bin_kernel   <<<eg1024, 1024, 0, stream>>>(ei, bcursor, pairs);
    bsort_kernel <<<NBUCK, 512, 0, stream>>>(boff, pairs, row_ptr, col, cold);

    prep_kernel  <<<NN * 128 / 4 / 256 + 96, 256, 0, stream>>>(x, W1, W2, xh, w1t, w2t);

    const int gemm_grid = (NN + 63) / 64;   // 782
    const int node_wave_grid = NN / 4;      // 12500 blocks (wave per node)

    // layer 1
    gemm1_mfma_kernel<<<gemm_grid, 256, 0, stream>>>(xh, w1t, at_s1, at_d1, h1h, as1, ad1);
    edge_w1_kernel   <<<eg256, 256, 0, stream>>>(col, cold, as1, ad1, (float4*)ex1);
    agg1_fused_kernel<<<node_wave_grid, 256, 0, stream>>>(row_ptr, col,
                        (const unsigned*)h1h, ex1, b1, (unsigned*)act1h);

    // layer 2
    gemm2_mfma_kernel<<<gemm_grid, 256, 0, stream>>>(act1h, w2t, at_s2, at_d2, h2h, as2, ad2);
    edge_w2_kernel   <<<eg256, 256, 0, stream>>>(col, cold, as2, ad2, ex2);
    agg2_fused_kernel<<<node_wave_grid, 256, 0, stream>>>(row_ptr, col, h2h, ex2, b2, out);
}

// Round 9
// 224.308 us; speedup vs baseline: 1.3896x; 1.2208x over previous
//
#include <hip/hip_runtime.h>

#define NN    50000      // nodes
#define NE    800000     // edges (without self loops)
#define NET   850000     // NE + NN (with self loops)
#define NBUCK ((NN + 255) / 256)   // 196 dst-buckets of 256 nodes
#define MAXB  8192       // padded slots per bucket (avg 4352, sigma 66)

typedef __fp16 half2_t __attribute__((ext_vector_type(2)));
typedef _Float16 half8 __attribute__((ext_vector_type(8)));
typedef float floatx4 __attribute__((ext_vector_type(4)));

__device__ __forceinline__ float lrelu(float v) { return fmaxf(v, 0.2f * v); }
__device__ __forceinline__ unsigned pk16(float a, float b) {
    half2_t h = __builtin_amdgcn_cvt_pkrtz(a, b);
    return __builtin_bit_cast(unsigned, h);
}
__device__ __forceinline__ float2 unpk16(unsigned u) {
    half2_t h = __builtin_bit_cast(half2_t, u);
    return make_float2((float)h.x, (float)h.y);
}

// ---------------------------------------------------------------------------
// prep: W1/W2 -> fp16 transposed [n][k]  (x conversion folded into gemm1)
// ---------------------------------------------------------------------------
__global__ void prep_w_kernel(const float* __restrict__ W1, const float* __restrict__ W2,
                              _Float16* __restrict__ w1t, _Float16* __restrict__ w2t)
{
    const int idx = blockIdx.x * 256 + threadIdx.x;  // 96*256 = 24576 exact
    if (idx < 16384) {
        const int k = idx >> 7, n = idx & 127;
        w1t[n * 128 + k] = (_Float16)W1[idx];
    } else {
        const int j = idx - 16384;
        const int k = j >> 6, n = j & 63;
        w2t[n * 128 + k] = (_Float16)W2[j];
    }
}

// ---------------------------------------------------------------------------
// MFMA GEMM1 + alpha1: h1h[N,128 fp16] = fp16(x) @ w1t^T; A packed from fp32
// x in-register (saves the xh round-trip). Epilogue via LDS (verified R8).
// ---------------------------------------------------------------------------
__global__ __launch_bounds__(256) void gemm1_mfma_kernel(
    const float* __restrict__ x, const _Float16* __restrict__ w1t,
    const float* __restrict__ att_s, const float* __restrict__ att_d,
    _Float16* __restrict__ h1h, float* __restrict__ as, float* __restrict__ ad)
{
    __shared__ _Float16 hs[64 * 128];   // 16 KB
    const int t    = threadIdx.x;
    const int lane = t & 63;
    const int m    = lane & 15;
    const int q    = lane >> 4;
    const int wv   = t >> 6;
    const int gr0  = blockIdx.x * 64;
    const int rbase = gr0 + wv * 16;

    const int rme = rbase + m;
    const int rc  = rme < NN ? rme : NN - 1;
    const float* ap = x + (size_t)rc * 128 + q * 8;

    floatx4 acc[8];
#pragma unroll
    for (int nt = 0; nt < 8; nt++) acc[nt] = (floatx4){0.f, 0.f, 0.f, 0.f};

#pragma unroll
    for (int ks = 0; ks < 4; ks++) {
        const float4 f0 = *(const float4*)(ap + ks * 32);
        const float4 f1 = *(const float4*)(ap + ks * 32 + 4);
        const uint4 au = make_uint4(pk16(f0.x, f0.y), pk16(f0.z, f0.w),
                                    pk16(f1.x, f1.y), pk16(f1.z, f1.w));
        const half8 a = __builtin_bit_cast(half8, au);
#pragma unroll
        for (int nt = 0; nt < 8; nt++) {
            const half8 b = *(const half8*)(w1t + (nt * 16 + m) * 128 + ks * 32 + q * 8);
            acc[nt] = __builtin_amdgcn_mfma_f32_16x16x32_f16(a, b, acc[nt], 0, 0, 0);
        }
    }

    const int lrow0 = wv * 16 + q * 4;
#pragma unroll
    for (int nt = 0; nt < 8; nt++)
#pragma unroll
        for (int r = 0; r < 4; r++)
            hs[(lrow0 + r) * 128 + nt * 16 + m] = (_Float16)acc[nt][r];
    __syncthreads();

#pragma unroll
    for (int i = t; i < 1024; i += 256) {
        const int row = i >> 4;
        if (gr0 + row < NN)
            ((half8*)h1h)[(size_t)(gr0 + row) * 16 + (i & 15)] = ((const half8*)hs)[i];
    }

    const int arow = t >> 2, hd = t & 3;
    const int grow = gr0 + arow;
    float ps = 0.f, pd = 0.f;
    const half8*  hp8 = (const half8*)(hs + arow * 128 + hd * 32);
    const float4* s4  = (const float4*)(att_s + hd * 32);
    const float4* d4  = (const float4*)(att_d + hd * 32);
#pragma unroll
    for (int cc = 0; cc < 4; cc++) {
        const half8 hv = hp8[cc];
        const float4 a = s4[cc * 2], b = s4[cc * 2 + 1];
        const float4 c = d4[cc * 2], e = d4[cc * 2 + 1];
        ps += (float)hv[0]*a.x + (float)hv[1]*a.y + (float)hv[2]*a.z + (float)hv[3]*a.w
            + (float)hv[4]*b.x + (float)hv[5]*b.y + (float)hv[6]*b.z + (float)hv[7]*b.w;
        pd += (float)hv[0]*c.x + (float)hv[1]*c.y + (float)hv[2]*c.z + (float)hv[3]*c.w
            + (float)hv[4]*e.x + (float)hv[5]*e.y + (float)hv[6]*e.z + (float)hv[7]*e.w;
    }
    if (grow < NN) {
        as[grow * 4 + hd] = ps;
        ad[grow * 4 + hd] = pd;
    }
}

// ---------------------------------------------------------------------------
// MFMA GEMM2 + alpha2 (verified R8)
// ---------------------------------------------------------------------------
__global__ __launch_bounds__(256) void gemm2_mfma_kernel(
    const _Float16* __restrict__ ah, const _Float16* __restrict__ w2t,
    const float* __restrict__ att_s, const float* __restrict__ att_d,
    _Float16* __restrict__ h2h, float* __restrict__ as, float* __restrict__ ad)
{
    __shared__ _Float16 hs[64 * 64];    // 8 KB
    const int t    = threadIdx.x;
    const int lane = t & 63;
    const int m    = lane & 15;
    const int q    = lane >> 4;
    const int wv   = t >> 6;
    const int gr0  = blockIdx.x * 64;
    const int rbase = gr0 + wv * 16;

    const int rme = rbase + m;
    const int rc  = rme < NN ? rme : NN - 1;
    const _Float16* ap = ah + (size_t)rc * 128 + q * 8;

    floatx4 acc[4];
#pragma unroll
    for (int nt = 0; nt < 4; nt++) acc[nt] = (floatx4){0.f, 0.f, 0.f, 0.f};

#pragma unroll
    for (int ks = 0; ks < 4; ks++) {
        const half8 a = *(const half8*)(ap + ks * 32);
#pragma unroll
        for (int nt = 0; nt < 4; nt++) {
            const half8 b = *(const half8*)(w2t + (nt * 16 + m) * 128 + ks * 32 + q * 8);
            acc[nt] = __builtin_amdgcn_mfma_f32_16x16x32_f16(a, b, acc[nt], 0, 0, 0);
        }
    }

    const int lrow0 = wv * 16 + q * 4;
#pragma unroll
    for (int nt = 0; nt < 4; nt++)
#pragma unroll
        for (int r = 0; r < 4; r++)
            hs[(lrow0 + r) * 64 + nt * 16 + m] = (_Float16)acc[nt][r];
    __syncthreads();

#pragma unroll
    for (int i = t; i < 512; i += 256) {
        const int row = i >> 3;
        if (gr0 + row < NN)
            ((half8*)h2h)[(size_t)(gr0 + row) * 8 + (i & 7)] = ((const half8*)hs)[i];
    }

    const int arow = t >> 2, sg = t & 3;
    const int grow = gr0 + arow;
    float ps = 0.f, pd = 0.f;
    const half8*  hp8 = (const half8*)(hs + arow * 64 + sg * 16);
    const float4* s4  = (const float4*)(att_s + sg * 16);
    const float4* d4  = (const float4*)(att_d + sg * 16);
#pragma unroll
    for (int cc = 0; cc < 2; cc++) {
        const half8 hv = hp8[cc];
        const float4 a = s4[cc * 2], b = s4[cc * 2 + 1];
        const float4 c = d4[cc * 2], e = d4[cc * 2 + 1];
        ps += (float)hv[0]*a.x + (float)hv[1]*a.y + (float)hv[2]*a.z + (float)hv[3]*a.w
            + (float)hv[4]*b.x + (float)hv[5]*b.y + (float)hv[6]*b.z + (float)hv[7]*b.w;
        pd += (float)hv[0]*c.x + (float)hv[1]*c.y + (float)hv[2]*c.z + (float)hv[3]*c.w
            + (float)hv[4]*e.x + (float)hv[5]*e.y + (float)hv[6]*e.z + (float)hv[7]*e.w;
    }
    ps += __shfl_down(ps, 2);  pd += __shfl_down(pd, 2);
    ps += __shfl_down(ps, 1);  pd += __shfl_down(pd, 1);
    if (sg == 0 && grow < NN) { as[grow] = ps; ad[grow] = pd; }
}

// ---------------------------------------------------------------------------
// CSR build v3: bin directly into padded bucket regions (no bcount/bscan),
// then per-bucket LDS counting sort. Bases via block-level atomicAdd on bcnt.
// ---------------------------------------------------------------------------
__global__ __launch_bounds__(1024) void bin_kernel(const int* __restrict__ ei,
                                                   int* __restrict__ bcnt,
                                                   uint2* __restrict__ pairs)
{
    __shared__ int hist[NBUCK], base[NBUCK], cur[NBUCK];
    const int t = threadIdx.x;
    if (t < NBUCK) { hist[t] = 0; cur[t] = 0; }
    __syncthreads();
    const int e = blockIdx.x * 1024 + t;
    int s = 0, d = 0, bk = 0;
    const bool ok = e < NET;
    if (ok) {
        if (e < NE) { s = ei[e]; d = ei[NE + e]; } else { s = d = e - NE; }
        bk = d >> 8;
        atomicAdd(&hist[bk], 1);
    }
    __syncthreads();
    if (t < NBUCK && hist[t]) base[t] = atomicAdd(&bcnt[t], hist[t]);
    __syncthreads();
    if (ok) {
        const int r = atomicAdd(&cur[bk], 1);
        pairs[(size_t)bk * MAXB + base[bk] + r] = make_uint2((unsigned)s, (unsigned)d);
    }
}

// bsort + fused edge_w1: sorts one bucket in LDS, emits row_beg/row_end,
// col/cold, AND ex1 (runs after gemm1 so as1/ad1 are ready; ad1 gathers are
// 4KB-local within the bucket's dst range).
__global__ __launch_bounds__(512) void bsort_ew1_kernel(
    const int* __restrict__ bcnt, const uint2* __restrict__ pairs,
    const float* __restrict__ as1, const float* __restrict__ ad1,
    int* __restrict__ row_beg, int* __restrict__ row_end,
    int* __restrict__ col, int* __restrict__ cold, float4* __restrict__ ex1)
{
    __shared__ int hist[256], cur[256], sh[256];
    __shared__ int outl[MAXB];
    __shared__ int outd[MAXB];
    const int b = blockIdx.x, t = threadIdx.x;
    const int m = bcnt[b];
    const int gbase = b * MAXB;
    if (t < 256) hist[t] = 0;
    __syncthreads();
    for (int i = t; i < m; i += 512)
        atomicAdd(&hist[pairs[gbase + i].y & 255], 1);
    __syncthreads();
    if (t < 256) sh[t] = hist[t];
    __syncthreads();
#pragma unroll
    for (int off = 1; off < 256; off <<= 1) {
        int u = (t < 256 && t >= off) ? sh[t - off] : 0;
        __syncthreads();
        if (t < 256) sh[t] += u;
        __syncthreads();
    }
    if (t < 256) {
        const int ex = sh[t] - hist[t];
        cur[t] = ex;
        const int node = (b << 8) + t;
        if (node < NN) {
            row_beg[node] = gbase + ex;
            row_end[node] = gbase + ex + hist[t];
        }
    }
    __syncthreads();
    for (int i = t; i < m; i += 512) {
        const uint2 p = pairs[gbase + i];
        const int r = atomicAdd(&cur[p.y & 255], 1);
        outl[r] = (int)p.x;
        outd[r] = (int)p.y;
    }
    __syncthreads();
    for (int i = t; i < m; i += 512) {
        const int s = outl[i], dd = outd[i];
        col[gbase + i]  = s;
        cold[gbase + i] = dd;
        const float4 a = ((const float4*)as1)[s];
        const float4 bb = ((const float4*)ad1)[dd];
        float4 v;
        v.x = __expf(lrelu(a.x + bb.x));
        v.y = __expf(lrelu(a.y + bb.y));
        v.z = __expf(lrelu(a.z + bb.z));
        v.w = __expf(lrelu(a.w + bb.w));
        ex1[gbase + i] = v;
    }
}

// ---------------------------------------------------------------------------
// edge_w2 over padded slots (32 blocks per bucket; tail blocks exit fast)
// ---------------------------------------------------------------------------
__global__ void edge_w2_kernel(const int* __restrict__ bcnt,
                               const int* __restrict__ col, const int* __restrict__ cold,
                               const float* __restrict__ as, const float* __restrict__ ad,
                               float* __restrict__ ex)
{
    const int bk    = blockIdx.x >> 5;                 // MAXB/256 = 32 blocks/bucket
    const int local = (blockIdx.x & 31) * 256 + threadIdx.x;
    if (local >= bcnt[bk]) return;
    const int j = bk * MAXB + local;
    ex[j] = __expf(lrelu(as[col[j]] + ad[cold[j]]));
}

// ---------------------------------------------------------------------------
// Fused layer-1 tail (verified R6-R8), padded-slot row_beg/row_end.
// ---------------------------------------------------------------------------
__global__ __launch_bounds__(256) void agg1_fused_kernel(
    const int* __restrict__ row_beg, const int* __restrict__ row_end,
    const int* __restrict__ col, const unsigned* __restrict__ hh,
    const float* __restrict__ exw, const float* __restrict__ b1,
    unsigned* __restrict__ acth)
{
    const int d    = __builtin_amdgcn_readfirstlane((blockIdx.x * 256 + threadIdx.x) >> 6);
    const int lane = threadIdx.x & 63;
    const int head = lane >> 4;
    const int beg = row_beg[d], end = row_end[d];       // s_loads (d uniform)

    float acc0 = 0.f, acc1 = 0.f, den = 0.f;
    int j = beg;
    for (; j + 16 <= end; j += 16) {
        float    w[16];
        unsigned g[16];
#pragma unroll
        for (int k = 0; k < 16; k++) {
            const int s = col[j + k];
            w[k] = exw[(j + k) * 4 + head];
            g[k] = hh[s * 64 + lane];
        }
#pragma unroll
        for (int k = 0; k < 16; k++) {
            const float2 g2 = unpk16(g[k]);
            den  += w[k];
            acc0 += w[k] * g2.x;
            acc1 += w[k] * g2.y;
        }
    }
    for (; j + 4 <= end; j += 4) {
        float    w[4];
        unsigned g[4];
#pragma unroll
        for (int k = 0; k < 4; k++) {
            const int s = col[j + k];
            w[k] = exw[(j + k) * 4 + head];
            g[k] = hh[s * 64 + lane];
        }
#pragma unroll
        for (int k = 0; k < 4; k++) {
            const float2 g2 = unpk16(g[k]);
            den  += w[k];
            acc0 += w[k] * g2.x;
            acc1 += w[k] * g2.y;
        }
    }
    for (; j < end; j++) {
        const float w = exw[j * 4 + head];
        const float2 g2 = unpk16(hh[col[j] * 64 + lane]);
        den  += w;
        acc0 += w * g2.x;
        acc1 += w * g2.y;
    }
    const float2 bb  = ((const float2*)b1)[lane];
    const float  inv = 1.f / (den + 1e-16f);
    float v0 = acc0 * inv + bb.x;
    float v1 = acc1 * inv + bb.y;
    v0 = v0 > 0.f ? v0 : (__expf(v0) - 1.f);
    v1 = v1 > 0.f ? v1 : (__expf(v1) - 1.f);
    acth[d * 64 + lane] = pk16(v0, v1);
}

// ---------------------------------------------------------------------------
// Fused layer-2 tail (verified R6-R8), padded-slot row_beg/row_end.
// ---------------------------------------------------------------------------
__global__ __launch_bounds__(256) void agg2_fused_kernel(
    const int* __restrict__ row_beg, const int* __restrict__ row_end,
    const int* __restrict__ col, const _Float16* __restrict__ h,
    const float* __restrict__ exw, const float* __restrict__ b2,
    float* __restrict__ out)
{
    const int d    = __builtin_amdgcn_readfirstlane((blockIdx.x * 256 + threadIdx.x) >> 6);
    const int lane = threadIdx.x & 63;
    const int beg = row_beg[d], end = row_end[d];

    float acc = 0.f, den = 0.f;
    int j = beg;
    for (; j + 16 <= end; j += 16) {
        float w[16], g[16];
#pragma unroll
        for (int k = 0; k < 16; k++) {
            const int s = col[j + k];
            w[k] = exw[j + k];
            g[k] = (float)h[s * 64 + lane];
        }
#pragma unroll
        for (int k = 0; k < 16; k++) {
            den += w[k];
            acc += w[k] * g[k];
        }
    }
    for (; j + 4 <= end; j += 4) {
        float w[4], g[4];
#pragma unroll
        for (int k = 0; k < 4; k++) {
            const int s = col[j + k];
            w[k] = exw[j + k];
            g[k] = (float)h[s * 64 + lane];
        }
#pragma unroll
        for (int k = 0; k < 4; k++) {
            den += w[k];
            acc += w[k] * g[k];
        }
    }
    for (; j < end; j++) {
        const float w = exw[j];
        den += w;
        acc += w * (float)h[col[j] * 64 + lane];
    }
    out[d * 64 + lane] = acc / (den + 1e-16f) + b2[lane];
}

// ---------------------------------------------------------------------------
extern "C" void kernel_launch(void* const* d_in, const int* in_sizes, int n_in,
                              void* d_out, int out_size, void* d_ws, size_t ws_size,
                              hipStream_t stream)
{
    const float* x    = (const float*)d_in[0];
    const int*   ei   = (const int*)  d_in[1];
    const float* W1   = (const float*)d_in[2];
    const float* at_s1= (const float*)d_in[3];
    const float* at_d1= (const float*)d_in[4];
    const float* b1   = (const float*)d_in[5];
    const float* W2   = (const float*)d_in[6];
    const float* at_s2= (const float*)d_in[7];
    const float* at_d2= (const float*)d_in[8];
    const float* b2   = (const float*)d_in[9];
    float*       out  = (float*)d_out;

    const size_t NPAD = (size_t)NBUCK * MAXB;   // 1,605,632 padded slots

    // workspace layout (~110 MB)
    float* fw   = (float*)d_ws;
    float* as1  = fw;                  // NN*4
    float* ad1  = as1  + NN * 4;       // NN*4
    float* as2  = ad1  + NN * 4;       // NN
    float* ad2  = as2  + NN;           // NN
    float* ex1  = ad2  + NN;           // NPAD*4 floats
    float* ex2  = ex1  + NPAD * 4;     // NPAD
    _Float16* h1h   = (_Float16*)(ex2 + NPAD); // NN*128
    _Float16* act1h = h1h  + (size_t)NN * 128; // NN*128
    _Float16* h2h   = act1h+ (size_t)NN * 128; // NN*64
    _Float16* w1t   = h2h  + (size_t)NN * 64;  // 16384
    _Float16* w2t   = w1t  + 16384;            // 8192
    int*   row_beg = (int*)(w2t + 8192);       // NN
    int*   row_end = row_beg + NN;             // NN
    int*   col     = row_end + NN;             // NPAD
    int*   cold    = col  + NPAD;              // NPAD
    int*   bcnt    = cold + NPAD;              // 256 (zeroed)
    uint2* pairs   = (uint2*)(bcnt + 256);     // NPAD uint2

    hipMemsetAsync(bcnt, 0, 256 * sizeof(int), stream);

    const int eg1024 = (NET + 1023) / 1024;
    const int gemm_grid = (NN + 63) / 64;   // 782
    const int node_wave_grid = NN / 4;      // 12500 blocks (wave per node)

    bin_kernel   <<<eg1024, 1024, 0, stream>>>(ei, bcnt, pairs);
    prep_w_kernel<<<96, 256, 0, stream>>>(W1, W2, w1t, w2t);

    // layer 1
    gemm1_mfma_kernel<<<gemm_grid, 256, 0, stream>>>(x, w1t, at_s1, at_d1, h1h, as1, ad1);
    bsort_ew1_kernel <<<NBUCK, 512, 0, stream>>>(bcnt, pairs, as1, ad1,
                        row_beg, row_end, col, cold, (float4*)ex1);
    agg1_fused_kernel<<<node_wave_grid, 256, 0, stream>>>(row_beg, row_end, col,
                        (const unsigned*)h1h, ex1, b1, (unsigned*)act1h);

    // layer 2
    gemm2_mfma_kernel<<<gemm_grid, 256, 0, stream>>>(act1h, w2t, at_s2, at_d2, h2h, as2, ad2);
    edge_w2_kernel   <<<NBUCK * 32, 256, 0, stream>>>(bcnt, col, cold, as2, ad2, ex2);
    agg2_fused_kernel<<<node_wave_grid, 256, 0, stream>>>(row_beg, row_end, col, h2h, ex2, b2, out);
}

// Round 10
// 216.212 us; speedup vs baseline: 1.4416x; 1.0374x over previous
//
#include <hip/hip_runtime.h>

#define NN    50000      // nodes
#define NE    800000     // edges (without self loops)
#define NET   850000     // NE + NN (with self loops)
#define NBUCK ((NN + 255) / 256)   // 196 dst-buckets of 256 nodes
#define MAXB  8192       // padded slots per bucket (avg 4352, sigma 66)

typedef __fp16 half2_t __attribute__((ext_vector_type(2)));
typedef _Float16 half8 __attribute__((ext_vector_type(8)));
typedef float floatx4 __attribute__((ext_vector_type(4)));

__device__ __forceinline__ float lrelu(float v) { return fmaxf(v, 0.2f * v); }
__device__ __forceinline__ unsigned pk16(float a, float b) {
    half2_t h = __builtin_amdgcn_cvt_pkrtz(a, b);
    return __builtin_bit_cast(unsigned, h);
}
__device__ __forceinline__ float2 unpk16(unsigned u) {
    half2_t h = __builtin_bit_cast(half2_t, u);
    return make_float2((float)h.x, (float)h.y);
}

// ---------------------------------------------------------------------------
// prep: W1/W2 -> fp16 transposed [n][k]
// ---------------------------------------------------------------------------
__global__ void prep_w_kernel(const float* __restrict__ W1, const float* __restrict__ W2,
                              _Float16* __restrict__ w1t, _Float16* __restrict__ w2t)
{
    const int idx = blockIdx.x * 256 + threadIdx.x;  // 96*256 = 24576 exact
    if (idx < 16384) {
        const int k = idx >> 7, n = idx & 127;
        w1t[n * 128 + k] = (_Float16)W1[idx];
    } else {
        const int j = idx - 16384;
        const int k = j >> 6, n = j & 63;
        w2t[n * 128 + k] = (_Float16)W2[j];
    }
}

// ---------------------------------------------------------------------------
// MFMA GEMM1 + alpha1 (verified R8/R9): fp32 x packed in-register.
// ---------------------------------------------------------------------------
__global__ __launch_bounds__(256) void gemm1_mfma_kernel(
    const float* __restrict__ x, const _Float16* __restrict__ w1t,
    const float* __restrict__ att_s, const float* __restrict__ att_d,
    _Float16* __restrict__ h1h, float* __restrict__ as, float* __restrict__ ad)
{
    __shared__ _Float16 hs[64 * 128];   // 16 KB
    const int t    = threadIdx.x;
    const int lane = t & 63;
    const int m    = lane & 15;
    const int q    = lane >> 4;
    const int wv   = t >> 6;
    const int gr0  = blockIdx.x * 64;
    const int rbase = gr0 + wv * 16;

    const int rme = rbase + m;
    const int rc  = rme < NN ? rme : NN - 1;
    const float* ap = x + (size_t)rc * 128 + q * 8;

    floatx4 acc[8];
#pragma unroll
    for (int nt = 0; nt < 8; nt++) acc[nt] = (floatx4){0.f, 0.f, 0.f, 0.f};

#pragma unroll
    for (int ks = 0; ks < 4; ks++) {
        const float4 f0 = *(const float4*)(ap + ks * 32);
        const float4 f1 = *(const float4*)(ap + ks * 32 + 4);
        const uint4 au = make_uint4(pk16(f0.x, f0.y), pk16(f0.z, f0.w),
                                    pk16(f1.x, f1.y), pk16(f1.z, f1.w));
        const half8 a = __builtin_bit_cast(half8, au);
#pragma unroll
        for (int nt = 0; nt < 8; nt++) {
            const half8 b = *(const half8*)(w1t + (nt * 16 + m) * 128 + ks * 32 + q * 8);
            acc[nt] = __builtin_amdgcn_mfma_f32_16x16x32_f16(a, b, acc[nt], 0, 0, 0);
        }
    }

    const int lrow0 = wv * 16 + q * 4;
#pragma unroll
    for (int nt = 0; nt < 8; nt++)
#pragma unroll
        for (int r = 0; r < 4; r++)
            hs[(lrow0 + r) * 128 + nt * 16 + m] = (_Float16)acc[nt][r];
    __syncthreads();

#pragma unroll
    for (int i = t; i < 1024; i += 256) {
        const int row = i >> 4;
        if (gr0 + row < NN)
            ((half8*)h1h)[(size_t)(gr0 + row) * 16 + (i & 15)] = ((const half8*)hs)[i];
    }

    const int arow = t >> 2, hd = t & 3;
    const int grow = gr0 + arow;
    float ps = 0.f, pd = 0.f;
    const half8*  hp8 = (const half8*)(hs + arow * 128 + hd * 32);
    const float4* s4  = (const float4*)(att_s + hd * 32);
    const float4* d4  = (const float4*)(att_d + hd * 32);
#pragma unroll
    for (int cc = 0; cc < 4; cc++) {
        const half8 hv = hp8[cc];
        const float4 a = s4[cc * 2], b = s4[cc * 2 + 1];
        const float4 c = d4[cc * 2], e = d4[cc * 2 + 1];
        ps += (float)hv[0]*a.x + (float)hv[1]*a.y + (float)hv[2]*a.z + (float)hv[3]*a.w
            + (float)hv[4]*b.x + (float)hv[5]*b.y + (float)hv[6]*b.z + (float)hv[7]*b.w;
        pd += (float)hv[0]*c.x + (float)hv[1]*c.y + (float)hv[2]*c.z + (float)hv[3]*c.w
            + (float)hv[4]*e.x + (float)hv[5]*e.y + (float)hv[6]*e.z + (float)hv[7]*e.w;
    }
    if (grow < NN) {
        as[grow * 4 + hd] = ps;
        ad[grow * 4 + hd] = pd;
    }
}

// ---------------------------------------------------------------------------
// MFMA GEMM2 + alpha2 (verified R8/R9)
// ---------------------------------------------------------------------------
__global__ __launch_bounds__(256) void gemm2_mfma_kernel(
    const _Float16* __restrict__ ah, const _Float16* __restrict__ w2t,
    const float* __restrict__ att_s, const float* __restrict__ att_d,
    _Float16* __restrict__ h2h, float* __restrict__ as, float* __restrict__ ad)
{
    __shared__ _Float16 hs[64 * 64];    // 8 KB
    const int t    = threadIdx.x;
    const int lane = t & 63;
    const int m    = lane & 15;
    const int q    = lane >> 4;
    const int wv   = t >> 6;
    const int gr0  = blockIdx.x * 64;
    const int rbase = gr0 + wv * 16;

    const int rme = rbase + m;
    const int rc  = rme < NN ? rme : NN - 1;
    const _Float16* ap = ah + (size_t)rc * 128 + q * 8;

    floatx4 acc[4];
#pragma unroll
    for (int nt = 0; nt < 4; nt++) acc[nt] = (floatx4){0.f, 0.f, 0.f, 0.f};

#pragma unroll
    for (int ks = 0; ks < 4; ks++) {
        const half8 a = *(const half8*)(ap + ks * 32);
#pragma unroll
        for (int nt = 0; nt < 4; nt++) {
            const half8 b = *(const half8*)(w2t + (nt * 16 + m) * 128 + ks * 32 + q * 8);
            acc[nt] = __builtin_amdgcn_mfma_f32_16x16x32_f16(a, b, acc[nt], 0, 0, 0);
        }
    }

    const int lrow0 = wv * 16 + q * 4;
#pragma unroll
    for (int nt = 0; nt < 4; nt++)
#pragma unroll
        for (int r = 0; r < 4; r++)
            hs[(lrow0 + r) * 64 + nt * 16 + m] = (_Float16)acc[nt][r];
    __syncthreads();

#pragma unroll
    for (int i = t; i < 512; i += 256) {
        const int row = i >> 3;
        if (gr0 + row < NN)
            ((half8*)h2h)[(size_t)(gr0 + row) * 8 + (i & 7)] = ((const half8*)hs)[i];
    }

    const int arow = t >> 2, sg = t & 3;
    const int grow = gr0 + arow;
    float ps = 0.f, pd = 0.f;
    const half8*  hp8 = (const half8*)(hs + arow * 64 + sg * 16);
    const float4* s4  = (const float4*)(att_s + sg * 16);
    const float4* d4  = (const float4*)(att_d + sg * 16);
#pragma unroll
    for (int cc = 0; cc < 2; cc++) {
        const half8 hv = hp8[cc];
        const float4 a = s4[cc * 2], b = s4[cc * 2 + 1];
        const float4 c = d4[cc * 2], e = d4[cc * 2 + 1];
        ps += (float)hv[0]*a.x + (float)hv[1]*a.y + (float)hv[2]*a.z + (float)hv[3]*a.w
            + (float)hv[4]*b.x + (float)hv[5]*b.y + (float)hv[6]*b.z + (float)hv[7]*b.w;
        pd += (float)hv[0]*c.x + (float)hv[1]*c.y + (float)hv[2]*c.z + (float)hv[3]*c.w
            + (float)hv[4]*e.x + (float)hv[5]*e.y + (float)hv[6]*e.z + (float)hv[7]*e.w;
    }
    ps += __shfl_down(ps, 2);  pd += __shfl_down(pd, 2);
    ps += __shfl_down(ps, 1);  pd += __shfl_down(pd, 1);
    if (sg == 0 && grow < NN) { as[grow] = ps; ad[grow] = pd; }
}

// ---------------------------------------------------------------------------
// CSR build (verified R9): bin into padded buckets, per-bucket LDS sort.
// bsort no longer emits cold/ex1 (weights now computed in the agg kernels).
// ---------------------------------------------------------------------------
__global__ __launch_bounds__(1024) void bin_kernel(const int* __restrict__ ei,
                                                   int* __restrict__ bcnt,
                                                   uint2* __restrict__ pairs)
{
    __shared__ int hist[NBUCK], base[NBUCK], cur[NBUCK];
    const int t = threadIdx.x;
    if (t < NBUCK) { hist[t] = 0; cur[t] = 0; }
    __syncthreads();
    const int e = blockIdx.x * 1024 + t;
    int s = 0, d = 0, bk = 0;
    const bool ok = e < NET;
    if (ok) {
        if (e < NE) { s = ei[e]; d = ei[NE + e]; } else { s = d = e - NE; }
        bk = d >> 8;
        atomicAdd(&hist[bk], 1);
    }
    __syncthreads();
    if (t < NBUCK && hist[t]) base[t] = atomicAdd(&bcnt[t], hist[t]);
    __syncthreads();
    if (ok) {
        const int r = atomicAdd(&cur[bk], 1);
        pairs[(size_t)bk * MAXB + base[bk] + r] = make_uint2((unsigned)s, (unsigned)d);
    }
}

__global__ __launch_bounds__(512) void bsort_kernel(
    const int* __restrict__ bcnt, const uint2* __restrict__ pairs,
    int* __restrict__ row_beg, int* __restrict__ row_end,
    int* __restrict__ col)
{
    __shared__ int hist[256], cur[256], sh[256];
    __shared__ int outl[MAXB];
    const int b = blockIdx.x, t = threadIdx.x;
    const int m = bcnt[b];
    const int gbase = b * MAXB;
    if (t < 256) hist[t] = 0;
    __syncthreads();
    for (int i = t; i < m; i += 512)
        atomicAdd(&hist[pairs[gbase + i].y & 255], 1);
    __syncthreads();
    if (t < 256) sh[t] = hist[t];
    __syncthreads();
#pragma unroll
    for (int off = 1; off < 256; off <<= 1) {
        int u = (t < 256 && t >= off) ? sh[t - off] : 0;
        __syncthreads();
        if (t < 256) sh[t] += u;
        __syncthreads();
    }
    if (t < 256) {
        const int ex = sh[t] - hist[t];
        cur[t] = ex;
        const int node = (b << 8) + t;
        if (node < NN) {
            row_beg[node] = gbase + ex;
            row_end[node] = gbase + ex + hist[t];
        }
    }
    __syncthreads();
    for (int i = t; i < m; i += 512) {
        const uint2 p = pairs[gbase + i];
        const int r = atomicAdd(&cur[p.y & 255], 1);
        outl[r] = (int)p.x;
    }
    __syncthreads();
    for (int i = t; i < m; i += 512) col[gbase + i] = outl[i];
}

// ---------------------------------------------------------------------------
// Fused layer-1 tail v4: weights computed lane-parallel into per-wave LDS
// (lane=edge: one exp instr covers 64 edges, no redundancy), then broadcast
// ds_read in the accumulation loop. No ex table, no edge_w kernel.
// ---------------------------------------------------------------------------
__global__ __launch_bounds__(256) void agg1_fused_kernel(
    const int* __restrict__ row_beg, const int* __restrict__ row_end,
    const int* __restrict__ col, const unsigned* __restrict__ hh,
    const float* __restrict__ as1, const float* __restrict__ ad1,
    const float* __restrict__ b1, unsigned* __restrict__ acth)
{
    __shared__ float wbuf[4][64 * 4];   // [wave][edge*4+head], 4 KB
    const int wv   = threadIdx.x >> 6;
    const int d    = __builtin_amdgcn_readfirstlane((blockIdx.x * 256 + threadIdx.x) >> 6);
    const int lane = threadIdx.x & 63;
    const int head = lane >> 4;
    const int beg = row_beg[d], end = row_end[d];       // s_loads (d uniform)
    const float4 ad4 = ((const float4*)ad1)[d];
    float* wb = wbuf[wv];

    float acc0 = 0.f, acc1 = 0.f, den = 0.f;

    for (int jb = beg; jb < end; jb += 64) {
        const int cnt = min(64, end - jb);
        // prologue: lane computes edge (jb+lane)'s 4 head-weights
        {
            const int sl = col[jb + min(lane, cnt - 1)];
            const float4 a = ((const float4*)as1)[sl];
            float4 w4;
            w4.x = __expf(lrelu(a.x + ad4.x));
            w4.y = __expf(lrelu(a.y + ad4.y));
            w4.z = __expf(lrelu(a.z + ad4.z));
            w4.w = __expf(lrelu(a.w + ad4.w));
            ((float4*)wb)[lane] = w4;
        }
        __asm__ volatile("s_waitcnt lgkmcnt(0)" ::: "memory");

        int k = 0;
        for (; k + 16 <= cnt; k += 16) {
            float    w[16];
            unsigned g[16];
#pragma unroll
            for (int u = 0; u < 16; u++) {
                const int s = col[jb + k + u];        // s_load (uniform)
                w[u] = wb[(k + u) * 4 + head];        // ds_read (broadcast x16)
                g[u] = hh[s * 64 + lane];             // saddr + voffset
            }
#pragma unroll
            for (int u = 0; u < 16; u++) {
                const float2 g2 = unpk16(g[u]);
                den  += w[u];
                acc0 += w[u] * g2.x;
                acc1 += w[u] * g2.y;
            }
        }
        for (; k + 4 <= cnt; k += 4) {
            float    w[4];
            unsigned g[4];
#pragma unroll
            for (int u = 0; u < 4; u++) {
                const int s = col[jb + k + u];
                w[u] = wb[(k + u) * 4 + head];
                g[u] = hh[s * 64 + lane];
            }
#pragma unroll
            for (int u = 0; u < 4; u++) {
                const float2 g2 = unpk16(g[u]);
                den  += w[u];
                acc0 += w[u] * g2.x;
                acc1 += w[u] * g2.y;
            }
        }
        for (; k < cnt; k++) {
            const float w = wb[k * 4 + head];
            const float2 g2 = unpk16(hh[col[jb + k] * 64 + lane]);
            den  += w;
            acc0 += w * g2.x;
            acc1 += w * g2.y;
        }
        __asm__ volatile("" ::: "memory");   // keep next chunk's writes after reads
    }
    const float2 bb  = ((const float2*)b1)[lane];
    const float  inv = 1.f / (den + 1e-16f);
    float v0 = acc0 * inv + bb.x;
    float v1 = acc1 * inv + bb.y;
    v0 = v0 > 0.f ? v0 : (__expf(v0) - 1.f);
    v1 = v1 > 0.f ? v1 : (__expf(v1) - 1.f);
    acth[d * 64 + lane] = pk16(v0, v1);
}

// ---------------------------------------------------------------------------
// Fused layer-2 tail v4: same LDS-staged weights (scalar per edge).
// ---------------------------------------------------------------------------
__global__ __launch_bounds__(256) void agg2_fused_kernel(
    const int* __restrict__ row_beg, const int* __restrict__ row_end,
    const int* __restrict__ col, const _Float16* __restrict__ h,
    const float* __restrict__ as2, const float* __restrict__ ad2,
    const float* __restrict__ b2, float* __restrict__ out)
{
    __shared__ float wbuf[4][64];   // 1 KB
    const int wv   = threadIdx.x >> 6;
    const int d    = __builtin_amdgcn_readfirstlane((blockIdx.x * 256 + threadIdx.x) >> 6);
    const int lane = threadIdx.x & 63;
    const int beg = row_beg[d], end = row_end[d];
    const float add = ad2[d];
    float* wb = wbuf[wv];

    float acc = 0.f, den = 0.f;

    for (int jb = beg; jb < end; jb += 64) {
        const int cnt = min(64, end - jb);
        {
            const int sl = col[jb + min(lane, cnt - 1)];
            wb[lane] = __expf(lrelu(as2[sl] + add));
        }
        __asm__ volatile("s_waitcnt lgkmcnt(0)" ::: "memory");

        int k = 0;
        for (; k + 16 <= cnt; k += 16) {
            float w[16], g[16];
#pragma unroll
            for (int u = 0; u < 16; u++) {
                const int s = col[jb + k + u];
                w[u] = wb[k + u];
                g[u] = (float)h[s * 64 + lane];
            }
#pragma unroll
            for (int u = 0; u < 16; u++) {
                den += w[u];
                acc += w[u] * g[u];
            }
        }
        for (; k + 4 <= cnt; k += 4) {
            float w[4], g[4];
#pragma unroll
            for (int u = 0; u < 4; u++) {
                const int s = col[jb + k + u];
                w[u] = wb[k + u];
                g[u] = (float)h[s * 64 + lane];
            }
#pragma unroll
            for (int u = 0; u < 4; u++) {
                den += w[u];
                acc += w[u] * g[u];
            }
        }
        for (; k < cnt; k++) {
            const float w = wb[k];
            den += w;
            acc += w * (float)h[col[jb + k] * 64 + lane];
        }
        __asm__ volatile("" ::: "memory");
    }
    out[d * 64 + lane] = acc / (den + 1e-16f) + b2[lane];
}

// ---------------------------------------------------------------------------
extern "C" void kernel_launch(void* const* d_in, const int* in_sizes, int n_in,
                              void* d_out, int out_size, void* d_ws, size_t ws_size,
                              hipStream_t stream)
{
    const float* x    = (const float*)d_in[0];
    const int*   ei   = (const int*)  d_in[1];
    const float* W1   = (const float*)d_in[2];
    const float* at_s1= (const float*)d_in[3];
    const float* at_d1= (const float*)d_in[4];
    const float* b1   = (const float*)d_in[5];
    const float* W2   = (const float*)d_in[6];
    const float* at_s2= (const float*)d_in[7];
    const float* at_d2= (const float*)d_in[8];
    const float* b2   = (const float*)d_in[9];
    float*       out  = (float*)d_out;

    const size_t NPAD = (size_t)NBUCK * MAXB;   // 1,605,632 padded slots

    // workspace layout (~55 MB)
    float* fw   = (float*)d_ws;
    float* as1  = fw;                  // NN*4
    float* ad1  = as1  + NN * 4;       // NN*4
    float* as2  = ad1  + NN * 4;       // NN
    float* ad2  = as2  + NN;           // NN
    _Float16* h1h   = (_Float16*)(ad2 + NN);   // NN*128
    _Float16* act1h = h1h  + (size_t)NN * 128; // NN*128
    _Float16* h2h   = act1h+ (size_t)NN * 128; // NN*64
    _Float16* w1t   = h2h  + (size_t)NN * 64;  // 16384
    _Float16* w2t   = w1t  + 16384;            // 8192
    int*   row_beg = (int*)(w2t + 8192);       // NN
    int*   row_end = row_beg + NN;             // NN
    int*   col     = row_end + NN;             // NPAD
    int*   bcnt    = col + NPAD;               // 256 (zeroed)
    uint2* pairs   = (uint2*)(bcnt + 256);     // NPAD uint2

    hipMemsetAsync(bcnt, 0, 256 * sizeof(int), stream);

    const int eg1024 = (NET + 1023) / 1024;
    const int gemm_grid = (NN + 63) / 64;   // 782
    const int node_wave_grid = NN / 4;      // 12500 blocks (wave per node)

    bin_kernel   <<<eg1024, 1024, 0, stream>>>(ei, bcnt, pairs);
    prep_w_kernel<<<96, 256, 0, stream>>>(W1, W2, w1t, w2t);
    bsort_kernel <<<NBUCK, 512, 0, stream>>>(bcnt, pairs, row_beg, row_end, col);

    // layer 1
    gemm1_mfma_kernel<<<gemm_grid, 256, 0, stream>>>(x, w1t, at_s1, at_d1, h1h, as1, ad1);
    agg1_fused_kernel<<<node_wave_grid, 256, 0, stream>>>(row_beg, row_end, col,
                        (const unsigned*)h1h, as1, ad1, b1, (unsigned*)act1h);

    // layer 2
    gemm2_mfma_kernel<<<gemm_grid, 256, 0, stream>>>(act1h, w2t, at_s2, at_d2, h2h, as2, ad2);
    agg2_fused_kernel<<<node_wave_grid, 256, 0, stream>>>(row_beg, row_end, col,
                        h2h, as2, ad2, b2, out);
}

// Round 11
// 211.403 us; speedup vs baseline: 1.4744x; 1.0227x over previous
//
#include <hip/hip_runtime.h>

#define NN    50000      // nodes
#define NE    800000     // edges (without self loops)
#define NET   850000     // NE + NN (with self loops)
#define NBUCK ((NN + 255) / 256)   // 196 dst-buckets of 256 nodes
#define MAXB  8192       // padded slots per bucket (avg 4352, sigma 66)

typedef __fp16 half2_t __attribute__((ext_vector_type(2)));
typedef _Float16 half8 __attribute__((ext_vector_type(8)));
typedef float floatx4 __attribute__((ext_vector_type(4)));

__device__ __forceinline__ float lrelu(float v) { return fmaxf(v, 0.2f * v); }
__device__ __forceinline__ unsigned pk16(float a, float b) {
    half2_t h = __builtin_amdgcn_cvt_pkrtz(a, b);
    return __builtin_bit_cast(unsigned, h);
}
__device__ __forceinline__ float2 unpk16(unsigned u) {
    half2_t h = __builtin_bit_cast(half2_t, u);
    return make_float2((float)h.x, (float)h.y);
}

// ---------------------------------------------------------------------------
// MFMA GEMM1 + alpha1 (verified R8-R10): fp32 x packed in-register.
// ---------------------------------------------------------------------------
__global__ __launch_bounds__(256) void gemm1_mfma_kernel(
    const float* __restrict__ x, const _Float16* __restrict__ w1t,
    const float* __restrict__ att_s, const float* __restrict__ att_d,
    _Float16* __restrict__ h1h, float* __restrict__ as, float* __restrict__ ad)
{
    __shared__ _Float16 hs[64 * 128];   // 16 KB
    const int t    = threadIdx.x;
    const int lane = t & 63;
    const int m    = lane & 15;
    const int q    = lane >> 4;
    const int wv   = t >> 6;
    const int gr0  = blockIdx.x * 64;
    const int rbase = gr0 + wv * 16;

    const int rme = rbase + m;
    const int rc  = rme < NN ? rme : NN - 1;
    const float* ap = x + (size_t)rc * 128 + q * 8;

    floatx4 acc[8];
#pragma unroll
    for (int nt = 0; nt < 8; nt++) acc[nt] = (floatx4){0.f, 0.f, 0.f, 0.f};

#pragma unroll
    for (int ks = 0; ks < 4; ks++) {
        const float4 f0 = *(const float4*)(ap + ks * 32);
        const float4 f1 = *(const float4*)(ap + ks * 32 + 4);
        const uint4 au = make_uint4(pk16(f0.x, f0.y), pk16(f0.z, f0.w),
                                    pk16(f1.x, f1.y), pk16(f1.z, f1.w));
        const half8 a = __builtin_bit_cast(half8, au);
#pragma unroll
        for (int nt = 0; nt < 8; nt++) {
            const half8 b = *(const half8*)(w1t + (nt * 16 + m) * 128 + ks * 32 + q * 8);
            acc[nt] = __builtin_amdgcn_mfma_f32_16x16x32_f16(a, b, acc[nt], 0, 0, 0);
        }
    }

    const int lrow0 = wv * 16 + q * 4;
#pragma unroll
    for (int nt = 0; nt < 8; nt++)
#pragma unroll
        for (int r = 0; r < 4; r++)
            hs[(lrow0 + r) * 128 + nt * 16 + m] = (_Float16)acc[nt][r];
    __syncthreads();

#pragma unroll
    for (int i = t; i < 1024; i += 256) {
        const int row = i >> 4;
        if (gr0 + row < NN)
            ((half8*)h1h)[(size_t)(gr0 + row) * 16 + (i & 15)] = ((const half8*)hs)[i];
    }

    const int arow = t >> 2, hd = t & 3;
    const int grow = gr0 + arow;
    float ps = 0.f, pd = 0.f;
    const half8*  hp8 = (const half8*)(hs + arow * 128 + hd * 32);
    const float4* s4  = (const float4*)(att_s + hd * 32);
    const float4* d4  = (const float4*)(att_d + hd * 32);
#pragma unroll
    for (int cc = 0; cc < 4; cc++) {
        const half8 hv = hp8[cc];
        const float4 a = s4[cc * 2], b = s4[cc * 2 + 1];
        const float4 c = d4[cc * 2], e = d4[cc * 2 + 1];
        ps += (float)hv[0]*a.x + (float)hv[1]*a.y + (float)hv[2]*a.z + (float)hv[3]*a.w
            + (float)hv[4]*b.x + (float)hv[5]*b.y + (float)hv[6]*b.z + (float)hv[7]*b.w;
        pd += (float)hv[0]*c.x + (float)hv[1]*c.y + (float)hv[2]*c.z + (float)hv[3]*c.w
            + (float)hv[4]*e.x + (float)hv[5]*e.y + (float)hv[6]*e.z + (float)hv[7]*e.w;
    }
    if (grow < NN) {
        as[grow * 4 + hd] = ps;
        ad[grow * 4 + hd] = pd;
    }
}

// ---------------------------------------------------------------------------
// MFMA GEMM2 + alpha2 (verified R8-R10)
// ---------------------------------------------------------------------------
__global__ __launch_bounds__(256) void gemm2_mfma_kernel(
    const _Float16* __restrict__ ah, const _Float16* __restrict__ w2t,
    const float* __restrict__ att_s, const float* __restrict__ att_d,
    _Float16* __restrict__ h2h, float* __restrict__ as, float* __restrict__ ad)
{
    __shared__ _Float16 hs[64 * 64];    // 8 KB
    const int t    = threadIdx.x;
    const int lane = t & 63;
    const int m    = lane & 15;
    const int q    = lane >> 4;
    const int wv   = t >> 6;
    const int gr0  = blockIdx.x * 64;
    const int rbase = gr0 + wv * 16;

    const int rme = rbase + m;
    const int rc  = rme < NN ? rme : NN - 1;
    const _Float16* ap = ah + (size_t)rc * 128 + q * 8;

    floatx4 acc[4];
#pragma unroll
    for (int nt = 0; nt < 4; nt++) acc[nt] = (floatx4){0.f, 0.f, 0.f, 0.f};

#pragma unroll
    for (int ks = 0; ks < 4; ks++) {
        const half8 a = *(const half8*)(ap + ks * 32);
#pragma unroll
        for (int nt = 0; nt < 4; nt++) {
            const half8 b = *(const half8*)(w2t + (nt * 16 + m) * 128 + ks * 32 + q * 8);
            acc[nt] = __builtin_amdgcn_mfma_f32_16x16x32_f16(a, b, acc[nt], 0, 0, 0);
        }
    }

    const int lrow0 = wv * 16 + q * 4;
#pragma unroll
    for (int nt = 0; nt < 4; nt++)
#pragma unroll
        for (int r = 0; r < 4; r++)
            hs[(lrow0 + r) * 64 + nt * 16 + m] = (_Float16)acc[nt][r];
    __syncthreads();

#pragma unroll
    for (int i = t; i < 512; i += 256) {
        const int row = i >> 3;
        if (gr0 + row < NN)
            ((half8*)h2h)[(size_t)(gr0 + row) * 8 + (i & 7)] = ((const half8*)hs)[i];
    }

    const int arow = t >> 2, sg = t & 3;
    const int grow = gr0 + arow;
    float ps = 0.f, pd = 0.f;
    const half8*  hp8 = (const half8*)(hs + arow * 64 + sg * 16);
    const float4* s4  = (const float4*)(att_s + sg * 16);
    const float4* d4  = (const float4*)(att_d + sg * 16);
#pragma unroll
    for (int cc = 0; cc < 2; cc++) {
        const half8 hv = hp8[cc];
        const float4 a = s4[cc * 2], b = s4[cc * 2 + 1];
        const float4 c = d4[cc * 2], e = d4[cc * 2 + 1];
        ps += (float)hv[0]*a.x + (float)hv[1]*a.y + (float)hv[2]*a.z + (float)hv[3]*a.w
            + (float)hv[4]*b.x + (float)hv[5]*b.y + (float)hv[6]*b.z + (float)hv[7]*b.w;
        pd += (float)hv[0]*c.x + (float)hv[1]*c.y + (float)hv[2]*c.z + (float)hv[3]*c.w
            + (float)hv[4]*e.x + (float)hv[5]*e.y + (float)hv[6]*e.z + (float)hv[7]*e.w;
    }
    ps += __shfl_down(ps, 2);  pd += __shfl_down(pd, 2);
    ps += __shfl_down(ps, 1);  pd += __shfl_down(pd, 1);
    if (sg == 0 && grow < NN) { as[grow] = ps; ad[grow] = pd; }
}

// ---------------------------------------------------------------------------
// bin (+ folded W prep in blocks 0..23): pairs packed to uint32
// (src in bits 0..15 — NN<65536 — and dst-local in bits 16..23).
// ---------------------------------------------------------------------------
__global__ __launch_bounds__(1024) void bin_kernel(const int* __restrict__ ei,
                                                   const float* __restrict__ W1,
                                                   const float* __restrict__ W2,
                                                   _Float16* __restrict__ w1t,
                                                   _Float16* __restrict__ w2t,
                                                   int* __restrict__ bcnt,
                                                   unsigned* __restrict__ pairs)
{
    // folded weight prep: 24 blocks x 1024 = 24576 elements exact
    if (blockIdx.x < 24) {
        const int idx = blockIdx.x * 1024 + threadIdx.x;
        if (idx < 16384) {
            const int k = idx >> 7, n = idx & 127;
            w1t[n * 128 + k] = (_Float16)W1[idx];
        } else {
            const int j = idx - 16384;
            const int k = j >> 6, n = j & 63;
            w2t[n * 128 + k] = (_Float16)W2[j];
        }
    }

    __shared__ int hist[NBUCK], base[NBUCK], cur[NBUCK];
    const int t = threadIdx.x;
    if (t < NBUCK) { hist[t] = 0; cur[t] = 0; }
    __syncthreads();
    const int e = blockIdx.x * 1024 + t;
    int s = 0, d = 0, bk = 0;
    const bool ok = e < NET;
    if (ok) {
        if (e < NE) { s = ei[e]; d = ei[NE + e]; } else { s = d = e - NE; }
        bk = d >> 8;
        atomicAdd(&hist[bk], 1);
    }
    __syncthreads();
    if (t < NBUCK && hist[t]) base[t] = atomicAdd(&bcnt[t], hist[t]);
    __syncthreads();
    if (ok) {
        const int r = atomicAdd(&cur[bk], 1);
        pairs[(size_t)bk * MAXB + base[bk] + r] =
            (unsigned)s | ((unsigned)(d & 255) << 16);
    }
}

// ---------------------------------------------------------------------------
// bsort (1024 threads): per-bucket LDS counting sort, emits row_beg/row_end
// and src-only col. Packed pairs: src = p & 0xFFFF, dlocal = p >> 16.
// ---------------------------------------------------------------------------
__global__ __launch_bounds__(1024) void bsort_kernel(
    const int* __restrict__ bcnt, const unsigned* __restrict__ pairs,
    int* __restrict__ row_beg, int* __restrict__ row_end,
    int* __restrict__ col)
{
    __shared__ int hist[256], cur[256], sh[256];
    __shared__ int outl[MAXB];
    const int b = blockIdx.x, t = threadIdx.x;
    const int m = bcnt[b];
    const int gbase = b * MAXB;
    if (t < 256) hist[t] = 0;
    __syncthreads();
    for (int i = t; i < m; i += 1024)
        atomicAdd(&hist[pairs[gbase + i] >> 16], 1);
    __syncthreads();
    if (t < 256) sh[t] = hist[t];
    __syncthreads();
#pragma unroll
    for (int off = 1; off < 256; off <<= 1) {
        int u = (t < 256 && t >= off) ? sh[t - off] : 0;
        __syncthreads();
        if (t < 256) sh[t] += u;
        __syncthreads();
    }
    if (t < 256) {
        const int ex = sh[t] - hist[t];
        cur[t] = ex;
        const int node = (b << 8) + t;
        if (node < NN) {
            row_beg[node] = gbase + ex;
            row_end[node] = gbase + ex + hist[t];
        }
    }
    __syncthreads();
    for (int i = t; i < m; i += 1024) {
        const unsigned p = pairs[gbase + i];
        const int r = atomicAdd(&cur[p >> 16], 1);
        outl[r] = (int)(p & 0xFFFFu);
    }
    __syncthreads();
    for (int i = t; i < m; i += 1024) col[gbase + i] = outl[i];
}

// ---------------------------------------------------------------------------
// Fused layer-1 tail (verified R10): LDS-staged lane-parallel weights.
// ---------------------------------------------------------------------------
__global__ __launch_bounds__(256) void agg1_fused_kernel(
    const int* __restrict__ row_beg, const int* __restrict__ row_end,
    const int* __restrict__ col, const unsigned* __restrict__ hh,
    const float* __restrict__ as1, const float* __restrict__ ad1,
    const float* __restrict__ b1, unsigned* __restrict__ acth)
{
    __shared__ float wbuf[4][64 * 4];   // [wave][edge*4+head], 4 KB
    const int wv   = threadIdx.x >> 6;
    const int d    = __builtin_amdgcn_readfirstlane((blockIdx.x * 256 + threadIdx.x) >> 6);
    const int lane = threadIdx.x & 63;
    const int head = lane >> 4;
    const int beg = row_beg[d], end = row_end[d];       // s_loads (d uniform)
    const float4 ad4 = ((const float4*)ad1)[d];
    float* wb = wbuf[wv];

    float acc0 = 0.f, acc1 = 0.f, den = 0.f;

    for (int jb = beg; jb < end; jb += 64) {
        const int cnt = min(64, end - jb);
        {
            const int sl = col[jb + min(lane, cnt - 1)];
            const float4 a = ((const float4*)as1)[sl];
            float4 w4;
            w4.x = __expf(lrelu(a.x + ad4.x));
            w4.y = __expf(lrelu(a.y + ad4.y));
            w4.z = __expf(lrelu(a.z + ad4.z));
            w4.w = __expf(lrelu(a.w + ad4.w));
            ((float4*)wb)[lane] = w4;
        }
        __asm__ volatile("s_waitcnt lgkmcnt(0)" ::: "memory");

        int k = 0;
        for (; k + 16 <= cnt; k += 16) {
            float    w[16];
            unsigned g[16];
#pragma unroll
            for (int u = 0; u < 16; u++) {
                const int s = col[jb + k + u];        // s_load (uniform)
                w[u] = wb[(k + u) * 4 + head];        // ds_read broadcast
                g[u] = hh[s * 64 + lane];             // saddr + voffset
            }
#pragma unroll
            for (int u = 0; u < 16; u++) {
                const float2 g2 = unpk16(g[u]);
                den  += w[u];
                acc0 += w[u] * g2.x;
                acc1 += w[u] * g2.y;
            }
        }
        for (; k + 4 <= cnt; k += 4) {
            float    w[4];
            unsigned g[4];
#pragma unroll
            for (int u = 0; u < 4; u++) {
                const int s = col[jb + k + u];
                w[u] = wb[(k + u) * 4 + head];
                g[u] = hh[s * 64 + lane];
            }
#pragma unroll
            for (int u = 0; u < 4; u++) {
                const float2 g2 = unpk16(g[u]);
                den  += w[u];
                acc0 += w[u] * g2.x;
                acc1 += w[u] * g2.y;
            }
        }
        for (; k < cnt; k++) {
            const float w = wb[k * 4 + head];
            const float2 g2 = unpk16(hh[col[jb + k] * 64 + lane]);
            den  += w;
            acc0 += w * g2.x;
            acc1 += w * g2.y;
        }
        __asm__ volatile("" ::: "memory");
    }
    const float2 bb  = ((const float2*)b1)[lane];
    const float  inv = 1.f / (den + 1e-16f);
    float v0 = acc0 * inv + bb.x;
    float v1 = acc1 * inv + bb.y;
    v0 = v0 > 0.f ? v0 : (__expf(v0) - 1.f);
    v1 = v1 > 0.f ? v1 : (__expf(v1) - 1.f);
    acth[d * 64 + lane] = pk16(v0, v1);
}

// ---------------------------------------------------------------------------
// Fused layer-2 tail (verified R10)
// ---------------------------------------------------------------------------
__global__ __launch_bounds__(256) void agg2_fused_kernel(
    const int* __restrict__ row_beg, const int* __restrict__ row_end,
    const int* __restrict__ col, const _Float16* __restrict__ h,
    const float* __restrict__ as2, const float* __restrict__ ad2,
    const float* __restrict__ b2, float* __restrict__ out)
{
    __shared__ float wbuf[4][64];   // 1 KB
    const int wv   = threadIdx.x >> 6;
    const int d    = __builtin_amdgcn_readfirstlane((blockIdx.x * 256 + threadIdx.x) >> 6);
    const int lane = threadIdx.x & 63;
    const int beg = row_beg[d], end = row_end[d];
    const float add = ad2[d];
    float* wb = wbuf[wv];

    float acc = 0.f, den = 0.f;

    for (int jb = beg; jb < end; jb += 64) {
        const int cnt = min(64, end - jb);
        {
            const int sl = col[jb + min(lane, cnt - 1)];
            wb[lane] = __expf(lrelu(as2[sl] + add));
        }
        __asm__ volatile("s_waitcnt lgkmcnt(0)" ::: "memory");

        int k = 0;
        for (; k + 16 <= cnt; k += 16) {
            float w[16], g[16];
#pragma unroll
            for (int u = 0; u < 16; u++) {
                const int s = col[jb + k + u];
                w[u] = wb[k + u];
                g[u] = (float)h[s * 64 + lane];
            }
#pragma unroll
            for (int u = 0; u < 16; u++) {
                den += w[u];
                acc += w[u] * g[u];
            }
        }
        for (; k + 4 <= cnt; k += 4) {
            float w[4], g[4];
#pragma unroll
            for (int u = 0; u < 4; u++) {
                const int s = col[jb + k + u];
                w[u] = wb[k + u];
                g[u] = (float)h[s * 64 + lane];
            }
#pragma unroll
            for (int u = 0; u < 4; u++) {
                den += w[u];
                acc += w[u] * g[u];
            }
        }
        for (; k < cnt; k++) {
            const float w = wb[k];
            den += w;
            acc += w * (float)h[col[jb + k] * 64 + lane];
        }
        __asm__ volatile("" ::: "memory");
    }
    out[d * 64 + lane] = acc / (den + 1e-16f) + b2[lane];
}

// ---------------------------------------------------------------------------
extern "C" void kernel_launch(void* const* d_in, const int* in_sizes, int n_in,
                              void* d_out, int out_size, void* d_ws, size_t ws_size,
                              hipStream_t stream)
{
    const float* x    = (const float*)d_in[0];
    const int*   ei   = (const int*)  d_in[1];
    const float* W1   = (const float*)d_in[2];
    const float* at_s1= (const float*)d_in[3];
    const float* at_d1= (const float*)d_in[4];
    const float* b1   = (const float*)d_in[5];
    const float* W2   = (const float*)d_in[6];
    const float* at_s2= (const float*)d_in[7];
    const float* at_d2= (const float*)d_in[8];
    const float* b2   = (const float*)d_in[9];
    float*       out  = (float*)d_out;

    const size_t NPAD = (size_t)NBUCK * MAXB;   // 1,605,632 padded slots

    // workspace layout (~48 MB)
    float* fw   = (float*)d_ws;
    float* as1  = fw;                  // NN*4
    float* ad1  = as1  + NN * 4;       // NN*4
    float* as2  = ad1  + NN * 4;       // NN
    float* ad2  = as2  + NN;           // NN
    _Float16* h1h   = (_Float16*)(ad2 + NN);   // NN*128
    _Float16* act1h = h1h  + (size_t)NN * 128; // NN*128
    _Float16* h2h   = act1h+ (size_t)NN * 128; // NN*64
    _Float16* w1t   = h2h  + (size_t)NN * 64;  // 16384
    _Float16* w2t   = w1t  + 16384;            // 8192
    int*   row_beg = (int*)(w2t + 8192);       // NN
    int*   row_end = row_beg + NN;             // NN
    int*   col     = row_end + NN;             // NPAD
    int*   bcnt    = col + NPAD;               // 256 (zeroed)
    unsigned* pairs = (unsigned*)(bcnt + 256); // NPAD

    hipMemsetAsync(bcnt, 0, 256 * sizeof(int), stream);

    const int eg1024 = (NET + 1023) / 1024;
    const int gemm_grid = (NN + 63) / 64;   // 782
    const int node_wave_grid = NN / 4;      // 12500 blocks (wave per node)

    bin_kernel  <<<eg1024, 1024, 0, stream>>>(ei, W1, W2, w1t, w2t, bcnt, pairs);
    bsort_kernel<<<NBUCK, 1024, 0, stream>>>(bcnt, pairs, row_beg, row_end, col);

    // layer 1
    gemm1_mfma_kernel<<<gemm_grid, 256, 0, stream>>>(x, w1t, at_s1, at_d1, h1h, as1, ad1);
    agg1_fused_kernel<<<node_wave_grid, 256, 0, stream>>>(row_beg, row_end, col,
                        (const unsigned*)h1h, as1, ad1, b1, (unsigned*)act1h);

    // layer 2
    gemm2_mfma_kernel<<<gemm_grid, 256, 0, stream>>>(act1h, w2t, at_s2, at_d2, h2h, as2, ad2);
    agg2_fused_kernel<<<node_wave_grid, 256, 0, stream>>>(row_beg, row_end, col,
                        h2h, as2, ad2, b2, out);
}